// Round 1
// baseline (4004.632 us; speedup 1.0000x reference)
//
#include <hip/hip_runtime.h>
#include <hip/hip_bf16.h>
#include <stdint.h>

// ---------------------------------------------------------------------------
// Informer encoder forward (B=8,S=1024,D=512,H=8,Dh=64,FF=2048,3 layers)
// fp32 everywhere (correctness-first baseline).
// ---------------------------------------------------------------------------

#define SQ 1024
#define DM 512
#define NH 8
#define DH 64
#define DFF 2048
#define NTOP 35
#define ROWS 8192            // B*S
#define EPSF 1e-5f

// ---------------- Threefry-2x32 (exact JAX PRNG) ---------------------------
__device__ inline void tf_round(uint32_t& x0, uint32_t& x1, int r) {
    x0 += x1;
    x1 = (x1 << r) | (x1 >> (32 - r));
    x1 ^= x0;
}
__device__ inline uint2 tf2x32(uint32_t k0, uint32_t k1, uint32_t x0, uint32_t x1) {
    uint32_t ks2 = k0 ^ k1 ^ 0x1BD11BDAu;
    x0 += k0; x1 += k1;
    tf_round(x0,x1,13); tf_round(x0,x1,15); tf_round(x0,x1,26); tf_round(x0,x1,6);
    x0 += k1; x1 += ks2 + 1u;
    tf_round(x0,x1,17); tf_round(x0,x1,29); tf_round(x0,x1,16); tf_round(x0,x1,24);
    x0 += ks2; x1 += k0 + 2u;
    tf_round(x0,x1,13); tf_round(x0,x1,15); tf_round(x0,x1,26); tf_round(x0,x1,6);
    x0 += k0; x1 += k1 + 3u;
    tf_round(x0,x1,17); tf_round(x0,x1,29); tf_round(x0,x1,16); tf_round(x0,x1,24);
    x0 += k1; x1 += ks2 + 4u;
    tf_round(x0,x1,13); tf_round(x0,x1,15); tf_round(x0,x1,26); tf_round(x0,x1,6);
    x0 += ks2; x1 += k0 + 5u;
    return make_uint2(x0, x1);
}

// idx[l,s] for layer `lyr`: lower random bits of randint(fold_in(key(42),lyr),(1024,35),0,1024)
__global__ void idx_kernel(int lyr, int* __restrict__ idx) {
    int p = blockIdx.x * 256 + threadIdx.x;
    if (p >= SQ * NTOP) return;
    // folded layer key
    uint2 fk = tf2x32(0u, 42u, 0u, (uint32_t)lyr);
    // split -> k2 = (h(0,2).y, h(1,3).y)
    uint2 a = tf2x32(fk.x, fk.y, 0u, 2u);
    uint2 bb = tf2x32(fk.x, fk.y, 1u, 3u);
    uint32_t k20 = a.y, k21 = bb.y;
    const int half = (SQ * NTOP) / 2;  // 17920
    uint32_t bits;
    if (p < half) bits = tf2x32(k20, k21, (uint32_t)p, (uint32_t)(half + p)).x;
    else          bits = tf2x32(k20, k21, (uint32_t)(p - half), (uint32_t)p).y;
    idx[p] = (int)(bits & 1023u);   // % 1024 (span=1024, multiplier==0 path)
}

// ---------------- conv1d token embedding + positional embedding ------------
__global__ __launch_bounds__(256) void embed_kernel(const float* __restrict__ xe,
                                                    const float* __restrict__ tk,
                                                    float* __restrict__ X) {
    int row = blockIdx.x;            // b*1024+s
    int b = row >> 10, s = row & 1023;
    __shared__ float xv[9];
    int t = threadIdx.x;
    if (t < 9) {
        int w = t / 3, c = t % 3;
        int tt = s + w;              // index into padded seq [0,1026)
        int r = (tt == 0) ? 1023 : (tt <= 1024 ? tt - 1 : 0);
        xv[t] = xe[((size_t)b * SQ + r) * 3 + c];
    }
    __syncthreads();
    const float cdiv = 0.017988946039015984f;  // ln(10000)/512
    for (int d = t; d < DM; d += 256) {
        float acc = 0.f;
        #pragma unroll
        for (int wi = 0; wi < 9; ++wi) acc += xv[wi] * tk[wi * DM + d];
        int j2 = (d >> 1) * 2;
        float div = __expf(0.f) * expf(-cdiv * (float)j2);
        float ang = (float)s * div;
        float pe = (d & 1) ? cosf(ang) : sinf(ang);
        X[(size_t)row * DM + d] = acc + pe;
    }
}

// ---------------- fp32 tiled GEMM: C = A(MxK) @ W(NxK)^T + bias, opt GELU --
__device__ inline float gelu_f(float v) {
    return 0.5f * v * (1.0f + erff(v * 0.7071067811865476f));
}

__global__ __launch_bounds__(256) void gemm_kernel(const float* __restrict__ A,
                                                   const float* __restrict__ W,
                                                   const float* __restrict__ bias,
                                                   float* __restrict__ C,
                                                   int M, int N, int K, int act) {
    __shared__ float As[32][64];
    __shared__ float Bs[32][64];
    int bm = blockIdx.x << 6;
    int bn = blockIdx.y << 6;
    int t = threadIdx.x;
    int tx = t & 15, ty = t >> 4;
    float acc[4][4] = {{0.f}};
    const float* Ab = A + (size_t)bm * K;
    const float* Wb = W + (size_t)bn * K;
    for (int k0 = 0; k0 < K; k0 += 32) {
        #pragma unroll
        for (int i = 0; i < 2; ++i) {
            int f = (t << 1) + i;        // 0..511
            int row = f >> 3;            // 0..63
            int kq = (f & 7) << 2;       // 0..28 step 4
            float4 va = *reinterpret_cast<const float4*>(Ab + (size_t)row * K + k0 + kq);
            As[kq + 0][row] = va.x; As[kq + 1][row] = va.y;
            As[kq + 2][row] = va.z; As[kq + 3][row] = va.w;
            float4 vb = *reinterpret_cast<const float4*>(Wb + (size_t)row * K + k0 + kq);
            Bs[kq + 0][row] = vb.x; Bs[kq + 1][row] = vb.y;
            Bs[kq + 2][row] = vb.z; Bs[kq + 3][row] = vb.w;
        }
        __syncthreads();
        #pragma unroll
        for (int kk = 0; kk < 32; ++kk) {
            float4 a4 = *reinterpret_cast<const float4*>(&As[kk][ty << 2]);
            float4 b4 = *reinterpret_cast<const float4*>(&Bs[kk][tx << 2]);
            float av[4] = {a4.x, a4.y, a4.z, a4.w};
            float bv[4] = {b4.x, b4.y, b4.z, b4.w};
            #pragma unroll
            for (int i = 0; i < 4; ++i)
                #pragma unroll
                for (int j = 0; j < 4; ++j)
                    acc[i][j] = fmaf(av[i], bv[j], acc[i][j]);
        }
        __syncthreads();
    }
    int nb = bn + (tx << 2);
    float4 b4 = *reinterpret_cast<const float4*>(&bias[nb]);
    float bv[4] = {b4.x, b4.y, b4.z, b4.w};
    #pragma unroll
    for (int i = 0; i < 4; ++i) {
        int m = bm + (ty << 2) + i;
        float4 o;
        float ov[4];
        #pragma unroll
        for (int j = 0; j < 4; ++j) {
            float v = acc[i][j] + bv[j];
            if (act == 1) v = gelu_f(v);
            ov[j] = v;
        }
        o.x = ov[0]; o.y = ov[1]; o.z = ov[2]; o.w = ov[3];
        *reinterpret_cast<float4*>(&C[(size_t)m * N + nb]) = o;
    }
}

// ---------------- sparsity measure M = max_s(QK_s) - sum_s(QK_s)/L ---------
__global__ __launch_bounds__(256) void mscore_kernel(const float* __restrict__ Q,
                                                     const float* __restrict__ K,
                                                     const int* __restrict__ idx,
                                                     float* __restrict__ Mv) {
    int bh = blockIdx.x;                       // 64
    int l = blockIdx.y * 256 + threadIdx.x;    // 0..1023
    int b = bh >> 3, h = bh & 7;
    const float4* q = reinterpret_cast<const float4*>(Q + ((size_t)(b * SQ + l)) * DM + h * DH);
    float4 qr[16];
    #pragma unroll
    for (int i = 0; i < 16; ++i) qr[i] = q[i];
    float mx = -INFINITY, sm = 0.f;
    for (int s = 0; s < NTOP; ++s) {
        int ki = idx[l * NTOP + s];
        const float4* kr = reinterpret_cast<const float4*>(K + ((size_t)(b * SQ + ki)) * DM + h * DH);
        float d = 0.f;
        #pragma unroll
        for (int i = 0; i < 16; ++i) {
            float4 kv = kr[i];
            d += qr[i].x * kv.x + qr[i].y * kv.y + qr[i].z * kv.z + qr[i].w * kv.w;
        }
        mx = fmaxf(mx, d);
        sm += d;
    }
    Mv[bh * SQ + l] = mx - sm * (1.0f / (float)SQ);
}

// ---------------- top-35 argmax selection per (b,h) ------------------------
__global__ __launch_bounds__(256) void topk_kernel(const float* __restrict__ Mv,
                                                   int* __restrict__ Mtop) {
    int bh = blockIdx.x;
    __shared__ float vals[SQ];
    __shared__ float rv[256];
    __shared__ int ri[256];
    int t = threadIdx.x;
    for (int i = t; i < SQ; i += 256) vals[i] = Mv[bh * SQ + i];
    __syncthreads();
    for (int u = 0; u < NTOP; ++u) {
        float bvv = -INFINITY; int bi = 0x7fffffff;
        for (int i = t; i < SQ; i += 256) {
            float v = vals[i];
            if (v > bvv) { bvv = v; bi = i; }
        }
        rv[t] = bvv; ri[t] = bi;
        __syncthreads();
        for (int s = 128; s > 0; s >>= 1) {
            if (t < s) {
                if (rv[t + s] > rv[t] || (rv[t + s] == rv[t] && ri[t + s] < ri[t])) {
                    rv[t] = rv[t + s]; ri[t] = ri[t + s];
                }
            }
            __syncthreads();
        }
        if (t == 0) { Mtop[bh * NTOP + u] = ri[0]; vals[ri[0]] = -INFINITY; }
        __syncthreads();
    }
}

// ---------------- dense attention for the 35 selected queries --------------
__global__ __launch_bounds__(256) void attn_kernel(const float* __restrict__ Q,
                                                   const float* __restrict__ K,
                                                   const float* __restrict__ V,
                                                   const int* __restrict__ Mtop,
                                                   float* __restrict__ upd) {
    int bh = blockIdx.x, u = blockIdx.y;
    int b = bh >> 3, h = bh & 7;
    int l = Mtop[bh * NTOP + u];
    __shared__ float sc[SQ];
    __shared__ float red[256];
    __shared__ float qs[DH];
    int t = threadIdx.x;
    if (t < 16)
        reinterpret_cast<float4*>(qs)[t] =
            reinterpret_cast<const float4*>(Q + ((size_t)(b * SQ + l)) * DM + h * DH)[t];
    __syncthreads();
    float lmax = -INFINITY;
    for (int k = t; k < SQ; k += 256) {
        const float4* kr = reinterpret_cast<const float4*>(K + ((size_t)(b * SQ + k)) * DM + h * DH);
        float d = 0.f;
        #pragma unroll
        for (int i = 0; i < 16; ++i) {
            float4 kv = kr[i];
            float4 qv = reinterpret_cast<float4*>(qs)[i];
            d += qv.x * kv.x + qv.y * kv.y + qv.z * kv.z + qv.w * kv.w;
        }
        d *= 0.125f;   // 1/sqrt(64)
        sc[k] = d;
        lmax = fmaxf(lmax, d);
    }
    red[t] = lmax; __syncthreads();
    for (int s = 128; s > 0; s >>= 1) { if (t < s) red[t] = fmaxf(red[t], red[t + s]); __syncthreads(); }
    float mx = red[0];
    __syncthreads();
    float lsum = 0.f;
    for (int k = t; k < SQ; k += 256) { float e = expf(sc[k] - mx); sc[k] = e; lsum += e; }
    red[t] = lsum; __syncthreads();
    for (int s = 128; s > 0; s >>= 1) { if (t < s) red[t] += red[t + s]; __syncthreads(); }
    float inv = 1.0f / red[0];
    __syncthreads();
    int dh = t & 63, chunk = t >> 6;
    float acc = 0.f;
    for (int k = chunk * 256; k < chunk * 256 + 256; ++k)
        acc += sc[k] * V[((size_t)(b * SQ + k)) * DM + h * DH + dh];
    red[t] = acc; __syncthreads();
    if (t < 64)
        upd[((size_t)bh * NTOP + u) * DH + dh] =
            (red[t] + red[64 + t] + red[128 + t] + red[192 + t]) * inv;
}

// ---------------- V mean over sequence per (b,h,dh) ------------------------
__global__ __launch_bounds__(256) void meanv_kernel(const float* __restrict__ V,
                                                    float* __restrict__ meanV) {
    int bh = blockIdx.x;
    int t = threadIdx.x;
    int b = bh >> 3, h = bh & 7;
    int dh = t & 63, chunk = t >> 6;
    float acc = 0.f;
    for (int s = chunk * 256; s < chunk * 256 + 256; ++s)
        acc += V[((size_t)(b * SQ + s)) * DM + h * DH + dh];
    __shared__ float red[256];
    red[t] = acc; __syncthreads();
    if (t < 64)
        meanV[bh * DH + dh] = (red[t] + red[64 + t] + red[128 + t] + red[192 + t]) * (1.0f / (float)SQ);
}

// ---------------- build context: broadcast meanV, then scatter upd ---------
__global__ void ctxfill_kernel(const float* __restrict__ meanV, float* __restrict__ ctx) {
    int n = blockIdx.x * 256 + threadIdx.x;   // 0 .. 4194303
    int d = n & 511;
    int row = n >> 9;
    int b = row >> 10;
    int h = d >> 6, dh = d & 63;
    ctx[n] = meanV[((b << 3) + h) * DH + dh];
}

__global__ void scatter_kernel(const float* __restrict__ upd, const int* __restrict__ Mtop,
                               float* __restrict__ ctx) {
    int bh = blockIdx.x, u = blockIdx.y;
    int t = threadIdx.x;   // 64
    int b = bh >> 3, h = bh & 7;
    int l = Mtop[bh * NTOP + u];
    ctx[((size_t)(b * SQ + l)) * DM + h * DH + t] = upd[((size_t)bh * NTOP + u) * DH + t];
}

// ---------------- residual add + LayerNorm ---------------------------------
__global__ __launch_bounds__(256) void add_ln_kernel(const float* __restrict__ Av,
                                                     const float* __restrict__ Bv,
                                                     const float* __restrict__ g,
                                                     const float* __restrict__ be,
                                                     float* __restrict__ out) {
    int row = blockIdx.x;
    int t = threadIdx.x;
    size_t base = (size_t)row * DM;
    float v0 = Av[base + t] + Bv[base + t];
    float v1 = Av[base + 256 + t] + Bv[base + 256 + t];
    __shared__ float r1[256], r2[256];
    r1[t] = v0 + v1; r2[t] = v0 * v0 + v1 * v1;
    __syncthreads();
    for (int s = 128; s > 0; s >>= 1) {
        if (t < s) { r1[t] += r1[t + s]; r2[t] += r2[t + s]; }
        __syncthreads();
    }
    float mu = r1[0] * (1.0f / (float)DM);
    float var = r2[0] * (1.0f / (float)DM) - mu * mu;
    float rs = rsqrtf(var + EPSF);
    out[base + t] = (v0 - mu) * rs * g[t] + be[t];
    out[base + 256 + t] = (v1 - mu) * rs * g[t + 256] + be[t + 256];
}

// ---------------- final LN + GELU + mask -----------------------------------
__global__ __launch_bounds__(256) void final_kernel(const float* __restrict__ X,
                                                    const float* __restrict__ g,
                                                    const float* __restrict__ be,
                                                    const float* __restrict__ mark,
                                                    float* __restrict__ act) {
    int row = blockIdx.x;
    int t = threadIdx.x;
    size_t base = (size_t)row * DM;
    float v0 = X[base + t];
    float v1 = X[base + 256 + t];
    __shared__ float r1[256], r2[256];
    r1[t] = v0 + v1; r2[t] = v0 * v0 + v1 * v1;
    __syncthreads();
    for (int s = 128; s > 0; s >>= 1) {
        if (t < s) { r1[t] += r1[t + s]; r2[t] += r2[t + s]; }
        __syncthreads();
    }
    float mu = r1[0] * (1.0f / (float)DM);
    float var = r2[0] * (1.0f / (float)DM) - mu * mu;
    float rs = rsqrtf(var + EPSF);
    float mk = mark[row];
    float a0 = (v0 - mu) * rs * g[t] + be[t];
    float a1 = (v1 - mu) * rs * g[t + 256] + be[t + 256];
    act[base + t] = gelu_f(a0) * mk;
    act[base + 256 + t] = gelu_f(a1) * mk;
}

// ---------------- final projection (B,524288) @ (5,524288)^T + pb ----------
__global__ __launch_bounds__(256) void proj_kernel(const float* __restrict__ act,
                                                   const float* __restrict__ pw,
                                                   const float* __restrict__ pb,
                                                   float* __restrict__ out) {
    int bc = blockIdx.x;
    int b = bc / 5, c = bc % 5;
    const float4* a = reinterpret_cast<const float4*>(act + (size_t)b * (SQ * DM));
    const float4* w = reinterpret_cast<const float4*>(pw + (size_t)c * (SQ * DM));
    float s = 0.f;
    for (int i = threadIdx.x; i < (SQ * DM) / 4; i += 256) {
        float4 av = a[i], wv = w[i];
        s += av.x * wv.x + av.y * wv.y + av.z * wv.z + av.w * wv.w;
    }
    __shared__ float red[256];
    red[threadIdx.x] = s; __syncthreads();
    for (int sft = 128; sft > 0; sft >>= 1) {
        if (threadIdx.x < sft) red[threadIdx.x] += red[threadIdx.x + sft];
        __syncthreads();
    }
    if (threadIdx.x == 0) out[b * 5 + c] = red[0] + pb[c];
}

// ---------------------------------------------------------------------------
extern "C" void kernel_launch(void* const* d_in, const int* in_sizes, int n_in,
                              void* d_out, int out_size, void* d_ws, size_t ws_size,
                              hipStream_t stream) {
    (void)in_sizes; (void)n_in; (void)out_size; (void)ws_size;

    const float* x_enc      = (const float*)d_in[0];
    const float* x_mark_enc = (const float*)d_in[1];
    const float* token_k    = (const float*)d_in[2];
    const float* Wq = (const float*)d_in[3];
    const float* bq = (const float*)d_in[4];
    const float* Wk = (const float*)d_in[5];
    const float* bk = (const float*)d_in[6];
    const float* Wv = (const float*)d_in[7];
    const float* bv = (const float*)d_in[8];
    const float* Wo = (const float*)d_in[9];
    const float* bo = (const float*)d_in[10];
    const float* c1w = (const float*)d_in[11];
    const float* c1b = (const float*)d_in[12];
    const float* c2w = (const float*)d_in[13];
    const float* c2b = (const float*)d_in[14];
    const float* g1 = (const float*)d_in[15];
    const float* b1 = (const float*)d_in[16];
    const float* g2 = (const float*)d_in[17];
    const float* b2 = (const float*)d_in[18];
    const float* gf = (const float*)d_in[19];
    const float* bf = (const float*)d_in[20];
    const float* proj_w = (const float*)d_in[21];
    const float* proj_b = (const float*)d_in[22];
    float* out = (float*)d_out;

    // workspace layout (bytes); 16 MB activation buffers
    const size_t SZ = (size_t)ROWS * DM * 4;   // 16 MB
    char* wsb = (char*)d_ws;
    float* X    = (float*)(wsb + 0 * SZ);
    float* Qb   = (float*)(wsb + 1 * SZ);
    float* Kb   = (float*)(wsb + 2 * SZ);
    float* Vb   = (float*)(wsb + 3 * SZ);
    float* CTX  = (float*)(wsb + 4 * SZ);   // also final activations
    float* X1   = (float*)(wsb + 5 * SZ);
    float* NX   = (float*)(wsb + 6 * SZ);   // attn out-proj result / FFN2 result
    float* Y    = (float*)(wsb + 7 * SZ);   // FFN intermediate (M-chunked, 16 MB)
    char* smal  = wsb + 8 * SZ;
    float* Mbuf  = (float*)(smal);                      // 256 KB
    int*   IDX   = (int*)(smal + 262144);               // 140 KB
    int*   MTOP  = (int*)(smal + 262144 + 262144);      // 9 KB
    float* UPD   = (float*)(smal + 262144 + 262144 + 16384);        // 560 KB
    float* MEANV = (float*)(smal + 262144 + 262144 + 16384 + 1048576);

    embed_kernel<<<ROWS, 256, 0, stream>>>(x_enc, token_k, X);

    for (int lyr = 0; lyr < 3; ++lyr) {
        const float* Wq_l = Wq + (size_t)lyr * DM * DM;
        const float* bq_l = bq + (size_t)lyr * DM;
        const float* Wk_l = Wk + (size_t)lyr * DM * DM;
        const float* bk_l = bk + (size_t)lyr * DM;
        const float* Wv_l = Wv + (size_t)lyr * DM * DM;
        const float* bv_l = bv + (size_t)lyr * DM;
        const float* Wo_l = Wo + (size_t)lyr * DM * DM;
        const float* bo_l = bo + (size_t)lyr * DM;
        const float* c1w_l = c1w + (size_t)lyr * DFF * DM;
        const float* c1b_l = c1b + (size_t)lyr * DFF;
        const float* c2w_l = c2w + (size_t)lyr * DM * DFF;
        const float* c2b_l = c2b + (size_t)lyr * DM;
        const float* g1_l = g1 + (size_t)lyr * DM;
        const float* b1_l = b1 + (size_t)lyr * DM;
        const float* g2_l = g2 + (size_t)lyr * DM;
        const float* b2_l = b2 + (size_t)lyr * DM;

        dim3 gQKV(ROWS / 64, DM / 64);
        gemm_kernel<<<gQKV, 256, 0, stream>>>(X, Wq_l, bq_l, Qb, ROWS, DM, DM, 0);
        gemm_kernel<<<gQKV, 256, 0, stream>>>(X, Wk_l, bk_l, Kb, ROWS, DM, DM, 0);
        gemm_kernel<<<gQKV, 256, 0, stream>>>(X, Wv_l, bv_l, Vb, ROWS, DM, DM, 0);

        idx_kernel<<<(SQ * NTOP + 255) / 256, 256, 0, stream>>>(lyr, IDX);
        mscore_kernel<<<dim3(64, 4), 256, 0, stream>>>(Qb, Kb, IDX, Mbuf);
        topk_kernel<<<64, 256, 0, stream>>>(Mbuf, MTOP);
        attn_kernel<<<dim3(64, NTOP), 256, 0, stream>>>(Qb, Kb, Vb, MTOP, UPD);
        meanv_kernel<<<64, 256, 0, stream>>>(Vb, MEANV);
        ctxfill_kernel<<<(ROWS * DM) / 256, 256, 0, stream>>>(MEANV, CTX);
        scatter_kernel<<<dim3(64, NTOP), 64, 0, stream>>>(UPD, MTOP, CTX);

        gemm_kernel<<<gQKV, 256, 0, stream>>>(CTX, Wo_l, bo_l, NX, ROWS, DM, DM, 0);
        add_ln_kernel<<<ROWS, 256, 0, stream>>>(X, NX, g1_l, b1_l, X1);

        // FFN, chunked over M in 4 pieces of 2048 rows (Y stays 16 MB)
        for (int mc = 0; mc < 4; ++mc) {
            const float* x1c = X1 + (size_t)mc * 2048 * DM;
            float* nxc = NX + (size_t)mc * 2048 * DM;
            gemm_kernel<<<dim3(2048 / 64, DFF / 64), 256, 0, stream>>>(x1c, c1w_l, c1b_l, Y, 2048, DFF, DM, 1);
            gemm_kernel<<<dim3(2048 / 64, DM / 64), 256, 0, stream>>>(Y, c2w_l, c2b_l, nxc, 2048, DM, DFF, 0);
        }
        add_ln_kernel<<<ROWS, 256, 0, stream>>>(X1, NX, g2_l, b2_l, X);
    }

    final_kernel<<<ROWS, 256, 0, stream>>>(X, gf, bf, x_mark_enc, CTX);
    proj_kernel<<<40, 256, 0, stream>>>(CTX, proj_w, proj_b, out);
}

// Round 3
// 2575.243 us; speedup vs baseline: 1.5551x; 1.5551x over previous
//
#include <hip/hip_runtime.h>
#include <hip/hip_bf16.h>
#include <stdint.h>

// ---------------------------------------------------------------------------
// Informer encoder forward (B=8,S=1024,D=512,H=8,Dh=64,FF=2048,3 layers)
// Round 2 (resubmit): GEMMs on MFMA via split-bf16 (hi/lo, 3-term) ->
// fp32-level accuracy at bf16 matrix-core rates. Attention/selection exact fp32.
// ---------------------------------------------------------------------------

#define SQ 1024
#define DM 512
#define NH 8
#define DH 64
#define DFF 2048
#define NTOP 35
#define ROWS 8192            // B*S
#define QKVD 1536            // fused Q|K|V row stride
#define EPSF 1e-5f

typedef __attribute__((ext_vector_type(8))) short bf16x8;
typedef __attribute__((ext_vector_type(4))) float f32x4;

__device__ __forceinline__ void gload_lds16(const void* g, void* l) {
    __builtin_amdgcn_global_load_lds((const __attribute__((address_space(1))) void*)g,
                                     (__attribute__((address_space(3))) void*)l, 16, 0, 0);
}

__device__ inline float gelu_f(float v) {
    return 0.5f * v * (1.0f + erff(v * 0.7071067811865476f));
}

// ---------------- Threefry-2x32 (exact JAX PRNG) ---------------------------
__device__ inline void tf_round(uint32_t& x0, uint32_t& x1, int r) {
    x0 += x1;
    x1 = (x1 << r) | (x1 >> (32 - r));
    x1 ^= x0;
}
__device__ inline uint2 tf2x32(uint32_t k0, uint32_t k1, uint32_t x0, uint32_t x1) {
    uint32_t ks2 = k0 ^ k1 ^ 0x1BD11BDAu;
    x0 += k0; x1 += k1;
    tf_round(x0,x1,13); tf_round(x0,x1,15); tf_round(x0,x1,26); tf_round(x0,x1,6);
    x0 += k1; x1 += ks2 + 1u;
    tf_round(x0,x1,17); tf_round(x0,x1,29); tf_round(x0,x1,16); tf_round(x0,x1,24);
    x0 += ks2; x1 += k0 + 2u;
    tf_round(x0,x1,13); tf_round(x0,x1,15); tf_round(x0,x1,26); tf_round(x0,x1,6);
    x0 += k0; x1 += k1 + 3u;
    tf_round(x0,x1,17); tf_round(x0,x1,29); tf_round(x0,x1,16); tf_round(x0,x1,24);
    x0 += k1; x1 += ks2 + 4u;
    tf_round(x0,x1,13); tf_round(x0,x1,15); tf_round(x0,x1,26); tf_round(x0,x1,6);
    x0 += ks2; x1 += k0 + 5u;
    return make_uint2(x0, x1);
}

__global__ void idx_kernel(int lyr, int* __restrict__ idx) {
    int p = blockIdx.x * 256 + threadIdx.x;
    if (p >= SQ * NTOP) return;
    uint2 fk = tf2x32(0u, 42u, 0u, (uint32_t)lyr);
    uint2 a = tf2x32(fk.x, fk.y, 0u, 2u);
    uint2 bb = tf2x32(fk.x, fk.y, 1u, 3u);
    uint32_t k20 = a.y, k21 = bb.y;
    const int half = (SQ * NTOP) / 2;  // 17920
    uint32_t bits;
    if (p < half) bits = tf2x32(k20, k21, (uint32_t)p, (uint32_t)(half + p)).x;
    else          bits = tf2x32(k20, k21, (uint32_t)(p - half), (uint32_t)p).y;
    idx[p] = (int)(bits & 1023u);
}

// ---------------- conv1d token embedding + positional embedding ------------
__global__ __launch_bounds__(256) void embed_kernel(const float* __restrict__ xe,
                                                    const float* __restrict__ tk,
                                                    float* __restrict__ X) {
    int row = blockIdx.x;            // b*1024+s
    int b = row >> 10, s = row & 1023;
    __shared__ float xv[9];
    int t = threadIdx.x;
    if (t < 9) {
        int w = t / 3, c = t % 3;
        int tt = s + w;
        int r = (tt == 0) ? 1023 : (tt <= 1024 ? tt - 1 : 0);
        xv[t] = xe[((size_t)b * SQ + r) * 3 + c];
    }
    __syncthreads();
    const float cdiv = 0.017988946039015984f;  // ln(10000)/512
    for (int d = t; d < DM; d += 256) {
        float acc = 0.f;
        #pragma unroll
        for (int wi = 0; wi < 9; ++wi) acc += xv[wi] * tk[wi * DM + d];
        int j2 = (d >> 1) * 2;
        float div = expf(-cdiv * (float)j2);
        float ang = (float)s * div;
        float pe = (d & 1) ? cosf(ang) : sinf(ang);
        X[(size_t)row * DM + d] = acc + pe;
    }
}

// ---------------- fp32 -> bf16 hi/lo split ---------------------------------
__global__ __launch_bounds__(256) void split_kernel(const float* __restrict__ s,
                                                    __hip_bfloat16* __restrict__ h,
                                                    __hip_bfloat16* __restrict__ l,
                                                    int n4) {
    int i = blockIdx.x * 256 + threadIdx.x;
    if (i >= n4) return;
    float4 v = reinterpret_cast<const float4*>(s)[i];
    float vv[4] = {v.x, v.y, v.z, v.w};
    ushort hv[4], lv[4];
    #pragma unroll
    for (int j = 0; j < 4; ++j) {
        __hip_bfloat16 hb = __float2bfloat16(vv[j]);
        float res = vv[j] - __bfloat162float(hb);
        __hip_bfloat16 lb = __float2bfloat16(res);
        hv[j] = *reinterpret_cast<ushort*>(&hb);
        lv[j] = *reinterpret_cast<ushort*>(&lb);
    }
    reinterpret_cast<ushort4*>(h)[i] = make_ushort4(hv[0], hv[1], hv[2], hv[3]);
    reinterpret_cast<ushort4*>(l)[i] = make_ushort4(lv[0], lv[1], lv[2], lv[3]);
}

__global__ void catbias_kernel(const float* __restrict__ a, const float* __restrict__ b,
                               const float* __restrict__ c, float* __restrict__ o) {
    int t = threadIdx.x;   // 512
    o[t] = a[t]; o[512 + t] = b[t]; o[1024 + t] = c[t];
}

// ---------------- split-bf16 MFMA GEMM -------------------------------------
// C(MxN) = (Ah+Al)(MxK) @ (Wh+Wl)(NxK)^T + bias; virtual K' = 3K with
// segments A:[h,l,h], W:[h,h,l]. BM=128, BN_ in {128,64}, BK=32, 256 thr.
// OUTMODE 0: fp32 C.  OUTMODE 2: gelu then split-bf16 (Oh,Ol).
template<int BN_, int OUTMODE>
__global__ __launch_bounds__(256) void mfma_gemm(
    const __hip_bfloat16* __restrict__ Ah, const __hip_bfloat16* __restrict__ Al,
    const __hip_bfloat16* __restrict__ Wh, const __hip_bfloat16* __restrict__ Wl,
    const float* __restrict__ bias,
    float* __restrict__ C,
    __hip_bfloat16* __restrict__ Oh, __hip_bfloat16* __restrict__ Ol,
    int M, int N, int K) {
    constexpr int NI = BN_ / 32;           // b-frags per wave
    __shared__ __hip_bfloat16 As[128 * 32];
    __shared__ __hip_bfloat16 Bs[BN_ * 32];
    const int t = threadIdx.x;
    const int lane = t & 63, w = t >> 6;
    const int wm = w >> 1, wn = w & 1;
    const int bm = blockIdx.x * 128, bn = blockIdx.y * BN_;
    const int r15 = lane & 15, kc = lane >> 4;
    f32x4 acc[4][NI];
    #pragma unroll
    for (int mi = 0; mi < 4; ++mi)
        #pragma unroll
        for (int ni = 0; ni < NI; ++ni)
            acc[mi][ni] = (f32x4){0.f, 0.f, 0.f, 0.f};

    const int KT = 3 * K;
    for (int kp = 0; kp < KT; kp += 32) {
        int seg = (kp >= 2 * K) ? 2 : ((kp >= K) ? 1 : 0);
        int k0 = kp - seg * K;
        const __hip_bfloat16* Ab = (seg == 1) ? Al : Ah;
        const __hip_bfloat16* Bb = (seg == 2) ? Wl : Wh;
        // stage A tile (128x32 bf16 = 8KB), XOR-swizzled via pre-swizzled src
        #pragma unroll
        for (int i = 0; i < 2; ++i) {
            int slot = (w + i * 4) * 64 + lane;
            int row = slot >> 2, cp = slot & 3;
            int cl = cp ^ (row & 3);
            gload_lds16(Ab + (size_t)(bm + row) * K + k0 + cl * 8,
                        As + (w + i * 4) * 512);
        }
        // stage B tile
        #pragma unroll
        for (int i = 0; i < BN_ / 64; ++i) {
            int slot = (w + i * 4) * 64 + lane;
            int row = slot >> 2, cp = slot & 3;
            int cl = cp ^ (row & 3);
            gload_lds16(Bb + (size_t)(bn + row) * K + k0 + cl * 8,
                        Bs + (w + i * 4) * 512);
        }
        __syncthreads();
        bf16x8 a[4], b[NI];
        #pragma unroll
        for (int mi = 0; mi < 4; ++mi) {
            int row = wm * 64 + mi * 16 + r15;
            a[mi] = *reinterpret_cast<const bf16x8*>(As + row * 32 + ((kc ^ (row & 3)) << 3));
        }
        #pragma unroll
        for (int ni = 0; ni < NI; ++ni) {
            int row = wn * (BN_ / 2) + ni * 16 + r15;
            b[ni] = *reinterpret_cast<const bf16x8*>(Bs + row * 32 + ((kc ^ (row & 3)) << 3));
        }
        #pragma unroll
        for (int mi = 0; mi < 4; ++mi)
            #pragma unroll
            for (int ni = 0; ni < NI; ++ni)
                acc[mi][ni] = __builtin_amdgcn_mfma_f32_16x16x32_bf16(a[mi], b[ni], acc[mi][ni], 0, 0, 0);
        __syncthreads();
    }

    const int rq = lane >> 4;
    #pragma unroll
    for (int mi = 0; mi < 4; ++mi) {
        #pragma unroll
        for (int ni = 0; ni < NI; ++ni) {
            int n = bn + wn * (BN_ / 2) + ni * 16 + r15;
            float bz = bias[n];
            #pragma unroll
            for (int r = 0; r < 4; ++r) {
                int m = bm + wm * 64 + mi * 16 + rq * 4 + r;
                float v = acc[mi][ni][r] + bz;
                if constexpr (OUTMODE == 0) {
                    C[(size_t)m * N + n] = v;
                } else {
                    float g = gelu_f(v);
                    __hip_bfloat16 hb = __float2bfloat16(g);
                    float res = g - __bfloat162float(hb);
                    __hip_bfloat16 lb = __float2bfloat16(res);
                    Oh[(size_t)m * N + n] = hb;
                    Ol[(size_t)m * N + n] = lb;
                }
            }
        }
    }
}

// ---------------- sparsity measure M = max_s(QK_s) - sum_s(QK_s)/L ---------
// QKV fused layout: row stride 1536, Q at +0, K at +512, V at +1024.
__global__ __launch_bounds__(128) void mscore_kernel(const float* __restrict__ QKV,
                                                     const int* __restrict__ idx,
                                                     float* __restrict__ Mv) {
    int bh = blockIdx.x;                       // 64
    int l = blockIdx.y * 128 + threadIdx.x;    // 0..1023
    int b = bh >> 3, h = bh & 7;
    const float4* q = reinterpret_cast<const float4*>(QKV + ((size_t)(b * SQ + l)) * QKVD + h * DH);
    float4 qr[16];
    #pragma unroll
    for (int i = 0; i < 16; ++i) qr[i] = q[i];
    float mx = -INFINITY, sm = 0.f;
    for (int s = 0; s < NTOP; ++s) {
        int ki = idx[l * NTOP + s];
        const float4* kr = reinterpret_cast<const float4*>(QKV + ((size_t)(b * SQ + ki)) * QKVD + DM + h * DH);
        float d = 0.f;
        #pragma unroll
        for (int i = 0; i < 16; ++i) {
            float4 kv = kr[i];
            d += qr[i].x * kv.x + qr[i].y * kv.y + qr[i].z * kv.z + qr[i].w * kv.w;
        }
        mx = fmaxf(mx, d);
        sm += d;
    }
    Mv[bh * SQ + l] = mx - sm * (1.0f / (float)SQ);
}

// ---------------- top-35 argmax selection per (b,h) ------------------------
__global__ __launch_bounds__(256) void topk_kernel(const float* __restrict__ Mv,
                                                   int* __restrict__ Mtop) {
    int bh = blockIdx.x;
    __shared__ float vals[SQ];
    __shared__ float rv[256];
    __shared__ int ri[256];
    int t = threadIdx.x;
    for (int i = t; i < SQ; i += 256) vals[i] = Mv[bh * SQ + i];
    __syncthreads();
    for (int u = 0; u < NTOP; ++u) {
        float bvv = -INFINITY; int bi = 0x7fffffff;
        for (int i = t; i < SQ; i += 256) {
            float v = vals[i];
            if (v > bvv) { bvv = v; bi = i; }
        }
        rv[t] = bvv; ri[t] = bi;
        __syncthreads();
        for (int s = 128; s > 0; s >>= 1) {
            if (t < s) {
                if (rv[t + s] > rv[t] || (rv[t + s] == rv[t] && ri[t + s] < ri[t])) {
                    rv[t] = rv[t + s]; ri[t] = ri[t + s];
                }
            }
            __syncthreads();
        }
        if (t == 0) { Mtop[bh * NTOP + u] = ri[0]; vals[ri[0]] = -INFINITY; }
        __syncthreads();
    }
}

// ---------------- dense attention for the 35 selected queries --------------
__global__ __launch_bounds__(256) void attn_kernel(const float* __restrict__ QKV,
                                                   const int* __restrict__ Mtop,
                                                   float* __restrict__ upd) {
    int bh = blockIdx.x, u = blockIdx.y;
    int b = bh >> 3, h = bh & 7;
    int l = Mtop[bh * NTOP + u];
    __shared__ float sc[SQ];
    __shared__ float red[256];
    __shared__ float qs[DH];
    int t = threadIdx.x;
    if (t < 16)
        reinterpret_cast<float4*>(qs)[t] =
            reinterpret_cast<const float4*>(QKV + ((size_t)(b * SQ + l)) * QKVD + h * DH)[t];
    __syncthreads();
    float lmax = -INFINITY;
    for (int k = t; k < SQ; k += 256) {
        const float4* kr = reinterpret_cast<const float4*>(QKV + ((size_t)(b * SQ + k)) * QKVD + DM + h * DH);
        float d = 0.f;
        #pragma unroll
        for (int i = 0; i < 16; ++i) {
            float4 kv = kr[i];
            float4 qv = reinterpret_cast<float4*>(qs)[i];
            d += qv.x * kv.x + qv.y * kv.y + qv.z * kv.z + qv.w * kv.w;
        }
        d *= 0.125f;   // 1/sqrt(64)
        sc[k] = d;
        lmax = fmaxf(lmax, d);
    }
    red[t] = lmax; __syncthreads();
    for (int s = 128; s > 0; s >>= 1) { if (t < s) red[t] = fmaxf(red[t], red[t + s]); __syncthreads(); }
    float mx = red[0];
    __syncthreads();
    float lsum = 0.f;
    for (int k = t; k < SQ; k += 256) { float e = expf(sc[k] - mx); sc[k] = e; lsum += e; }
    red[t] = lsum; __syncthreads();
    for (int s = 128; s > 0; s >>= 1) { if (t < s) red[t] += red[t + s]; __syncthreads(); }
    float inv = 1.0f / red[0];
    __syncthreads();
    int dh = t & 63, chunk = t >> 6;
    float acc = 0.f;
    for (int k = chunk * 256; k < chunk * 256 + 256; ++k)
        acc += sc[k] * QKV[((size_t)(b * SQ + k)) * QKVD + 2 * DM + h * DH + dh];
    red[t] = acc; __syncthreads();
    if (t < 64)
        upd[((size_t)bh * NTOP + u) * DH + dh] =
            (red[t] + red[64 + t] + red[128 + t] + red[192 + t]) * inv;
}

// ---------------- V mean over sequence per (b,h,dh) ------------------------
__global__ __launch_bounds__(256) void meanv_kernel(const float* __restrict__ QKV,
                                                    float* __restrict__ meanV) {
    int bh = blockIdx.x;
    int t = threadIdx.x;
    int b = bh >> 3, h = bh & 7;
    int dh = t & 63, chunk = t >> 6;
    float acc = 0.f;
    for (int s = chunk * 256; s < chunk * 256 + 256; ++s)
        acc += QKV[((size_t)(b * SQ + s)) * QKVD + 2 * DM + h * DH + dh];
    __shared__ float red[256];
    red[t] = acc; __syncthreads();
    if (t < 64)
        meanV[bh * DH + dh] = (red[t] + red[64 + t] + red[128 + t] + red[192 + t]) * (1.0f / (float)SQ);
}

// ---------------- build context: broadcast meanV, then scatter upd ---------
__global__ void ctxfill_kernel(const float* __restrict__ meanV, float* __restrict__ ctx) {
    int n = blockIdx.x * 256 + threadIdx.x;   // 0 .. 4194303
    int d = n & 511;
    int row = n >> 9;
    int b = row >> 10;
    int h = d >> 6, dh = d & 63;
    ctx[n] = meanV[((b << 3) + h) * DH + dh];
}

__global__ void scatter_kernel(const float* __restrict__ upd, const int* __restrict__ Mtop,
                               float* __restrict__ ctx) {
    int bh = blockIdx.x, u = blockIdx.y;
    int t = threadIdx.x;   // 64
    int b = bh >> 3, h = bh & 7;
    int l = Mtop[bh * NTOP + u];
    ctx[((size_t)(b * SQ + l)) * DM + h * DH + t] = upd[((size_t)bh * NTOP + u) * DH + t];
}

// ---------------- residual add + LayerNorm ---------------------------------
__global__ __launch_bounds__(256) void add_ln_kernel(const float* __restrict__ Av,
                                                     const float* __restrict__ Bv,
                                                     const float* __restrict__ g,
                                                     const float* __restrict__ be,
                                                     float* __restrict__ out) {
    int row = blockIdx.x;
    int t = threadIdx.x;
    size_t base = (size_t)row * DM;
    float v0 = Av[base + t] + Bv[base + t];
    float v1 = Av[base + 256 + t] + Bv[base + 256 + t];
    __shared__ float r1[256], r2[256];
    r1[t] = v0 + v1; r2[t] = v0 * v0 + v1 * v1;
    __syncthreads();
    for (int s = 128; s > 0; s >>= 1) {
        if (t < s) { r1[t] += r1[t + s]; r2[t] += r2[t + s]; }
        __syncthreads();
    }
    float mu = r1[0] * (1.0f / (float)DM);
    float var = r2[0] * (1.0f / (float)DM) - mu * mu;
    float rs = rsqrtf(var + EPSF);
    out[base + t] = (v0 - mu) * rs * g[t] + be[t];
    out[base + 256 + t] = (v1 - mu) * rs * g[t + 256] + be[t + 256];
}

// ---------------- final LN + GELU + mask -----------------------------------
__global__ __launch_bounds__(256) void final_kernel(const float* __restrict__ X,
                                                    const float* __restrict__ g,
                                                    const float* __restrict__ be,
                                                    const float* __restrict__ mark,
                                                    float* __restrict__ act) {
    int row = blockIdx.x;
    int t = threadIdx.x;
    size_t base = (size_t)row * DM;
    float v0 = X[base + t];
    float v1 = X[base + 256 + t];
    __shared__ float r1[256], r2[256];
    r1[t] = v0 + v1; r2[t] = v0 * v0 + v1 * v1;
    __syncthreads();
    for (int s = 128; s > 0; s >>= 1) {
        if (t < s) { r1[t] += r1[t + s]; r2[t] += r2[t + s]; }
        __syncthreads();
    }
    float mu = r1[0] * (1.0f / (float)DM);
    float var = r2[0] * (1.0f / (float)DM) - mu * mu;
    float rs = rsqrtf(var + EPSF);
    float mk = mark[row];
    float a0 = (v0 - mu) * rs * g[t] + be[t];
    float a1 = (v1 - mu) * rs * g[t + 256] + be[t + 256];
    act[base + t] = gelu_f(a0) * mk;
    act[base + 256 + t] = gelu_f(a1) * mk;
}

// ---------------- final projection: two-stage ------------------------------
__global__ __launch_bounds__(256) void proj1_kernel(const float* __restrict__ act,
                                                    const float* __restrict__ pw,
                                                    float* __restrict__ part) {
    int bc = blockIdx.x;      // 40
    int sg = blockIdx.y;      // 16
    int b = bc / 5, c = bc % 5;
    const float4* a = reinterpret_cast<const float4*>(act + (size_t)b * (SQ * DM) + sg * 32768);
    const float4* w = reinterpret_cast<const float4*>(pw + (size_t)c * (SQ * DM) + sg * 32768);
    float s = 0.f;
    for (int i = threadIdx.x; i < 8192; i += 256) {
        float4 av = a[i], wv = w[i];
        s += av.x * wv.x + av.y * wv.y + av.z * wv.z + av.w * wv.w;
    }
    __shared__ float red[256];
    red[threadIdx.x] = s; __syncthreads();
    for (int sft = 128; sft > 0; sft >>= 1) {
        if (threadIdx.x < sft) red[threadIdx.x] += red[threadIdx.x + sft];
        __syncthreads();
    }
    if (threadIdx.x == 0) part[bc * 16 + sg] = red[0];
}

__global__ void proj2_kernel(const float* __restrict__ part, const float* __restrict__ pb,
                             float* __restrict__ out) {
    int t = threadIdx.x;  // 64
    if (t < 40) {
        float s = 0.f;
        #pragma unroll
        for (int i = 0; i < 16; ++i) s += part[t * 16 + i];
        out[t] = s + pb[t % 5];
    }
}

// ---------------------------------------------------------------------------
extern "C" void kernel_launch(void* const* d_in, const int* in_sizes, int n_in,
                              void* d_out, int out_size, void* d_ws, size_t ws_size,
                              hipStream_t stream) {
    (void)in_sizes; (void)n_in; (void)out_size; (void)ws_size;

    const float* x_enc      = (const float*)d_in[0];
    const float* x_mark_enc = (const float*)d_in[1];
    const float* token_k    = (const float*)d_in[2];
    const float* Wq = (const float*)d_in[3];
    const float* bq = (const float*)d_in[4];
    const float* Wk = (const float*)d_in[5];
    const float* bk = (const float*)d_in[6];
    const float* Wv = (const float*)d_in[7];
    const float* bv = (const float*)d_in[8];
    const float* Wo = (const float*)d_in[9];
    const float* bo = (const float*)d_in[10];
    const float* c1w = (const float*)d_in[11];
    const float* c1b = (const float*)d_in[12];
    const float* c2w = (const float*)d_in[13];
    const float* c2b = (const float*)d_in[14];
    const float* g1 = (const float*)d_in[15];
    const float* b1 = (const float*)d_in[16];
    const float* g2 = (const float*)d_in[17];
    const float* b2 = (const float*)d_in[18];
    const float* gf = (const float*)d_in[19];
    const float* bf = (const float*)d_in[20];
    const float* proj_w = (const float*)d_in[21];
    const float* proj_b = (const float*)d_in[22];
    float* out = (float*)d_out;

    const size_t MB = 1024 * 1024;
    char* wsb = (char*)d_ws;
    // fp32 regions
    float* X    = (float*)(wsb);                 // 16 MB
    float* QKVp = (float*)(wsb + 16 * MB);       // 48 MB fused QKV (8192x1536)
    float* CTXp = (float*)(wsb + 16 * MB);       // carve 1: reuse after attention
    float* NXp  = (float*)(wsb + 32 * MB);       // carve 2
    float* X1p  = (float*)(wsb + 48 * MB);       // carve 3
    // bf16 split buffers
    __hip_bfloat16* Ah  = (__hip_bfloat16*)(wsb + 64 * MB);   // 8 MB (8192x512)
    __hip_bfloat16* Al  = (__hip_bfloat16*)(wsb + 72 * MB);   // 8 MB
    __hip_bfloat16* Yh  = (__hip_bfloat16*)(wsb + 80 * MB);   // 16 MB (4096x2048)
    __hip_bfloat16* Yl  = (__hip_bfloat16*)(wsb + 96 * MB);   // 16 MB
    __hip_bfloat16* WhA = (__hip_bfloat16*)(wsb + 112 * MB);  // 2 MB
    __hip_bfloat16* WlA = (__hip_bfloat16*)(wsb + 114 * MB);  // 2 MB
    __hip_bfloat16* WhB = (__hip_bfloat16*)(wsb + 116 * MB);  // 2 MB
    __hip_bfloat16* WlB = (__hip_bfloat16*)(wsb + 118 * MB);  // 2 MB
    float* biasC = (float*)(wsb + 120 * MB);                  // 6 KB
    char* smal  = wsb + 121 * MB;
    float* Mbuf  = (float*)(smal);                            // 256 KB
    int*   IDX   = (int*)(smal + 262144);                     // 140 KB
    int*   MTOP  = (int*)(smal + 262144 + 262144);            // 9 KB
    float* UPD   = (float*)(smal + 262144 + 262144 + 16384);  // 560 KB
    float* MEANV = (float*)(smal + 262144 + 262144 + 16384 + 1048576);
    float* PART  = (float*)(smal + 262144 + 262144 + 16384 + 1048576 + 65536);

    embed_kernel<<<ROWS, 256, 0, stream>>>(x_enc, token_k, X);

    for (int lyr = 0; lyr < 3; ++lyr) {
        const float* Wq_l = Wq + (size_t)lyr * DM * DM;
        const float* bq_l = bq + (size_t)lyr * DM;
        const float* Wk_l = Wk + (size_t)lyr * DM * DM;
        const float* bk_l = bk + (size_t)lyr * DM;
        const float* Wv_l = Wv + (size_t)lyr * DM * DM;
        const float* bv_l = bv + (size_t)lyr * DM;
        const float* Wo_l = Wo + (size_t)lyr * DM * DM;
        const float* bo_l = bo + (size_t)lyr * DM;
        const float* c1w_l = c1w + (size_t)lyr * DFF * DM;
        const float* c1b_l = c1b + (size_t)lyr * DFF;
        const float* c2w_l = c2w + (size_t)lyr * DM * DFF;
        const float* c2b_l = c2b + (size_t)lyr * DM;
        const float* g1_l = g1 + (size_t)lyr * DM;
        const float* b1_l = b1 + (size_t)lyr * DM;
        const float* g2_l = g2 + (size_t)lyr * DM;
        const float* b2_l = b2 + (size_t)lyr * DM;

        // ---- fused QKV projection (N=1536) ----
        split_kernel<<<(ROWS * DM / 4 + 255) / 256, 256, 0, stream>>>(X, Ah, Al, ROWS * DM / 4);
        split_kernel<<<(DM * DM / 4 + 255) / 256, 256, 0, stream>>>(Wq_l, WhA, WlA, DM * DM / 4);
        split_kernel<<<(DM * DM / 4 + 255) / 256, 256, 0, stream>>>(Wk_l, WhA + DM * DM, WlA + DM * DM, DM * DM / 4);
        split_kernel<<<(DM * DM / 4 + 255) / 256, 256, 0, stream>>>(Wv_l, WhA + 2 * DM * DM, WlA + 2 * DM * DM, DM * DM / 4);
        catbias_kernel<<<1, 512, 0, stream>>>(bq_l, bk_l, bv_l, biasC);
        mfma_gemm<128, 0><<<dim3(ROWS / 128, QKVD / 128), 256, 0, stream>>>(
            Ah, Al, WhA, WlA, biasC, QKVp, nullptr, nullptr, ROWS, QKVD, DM);

        // ---- ProbSparse attention ----
        idx_kernel<<<(SQ * NTOP + 255) / 256, 256, 0, stream>>>(lyr, IDX);
        mscore_kernel<<<dim3(64, 8), 128, 0, stream>>>(QKVp, IDX, Mbuf);
        topk_kernel<<<64, 256, 0, stream>>>(Mbuf, MTOP);
        attn_kernel<<<dim3(64, NTOP), 256, 0, stream>>>(QKVp, MTOP, UPD);
        meanv_kernel<<<64, 256, 0, stream>>>(QKVp, MEANV);
        ctxfill_kernel<<<(ROWS * DM) / 256, 256, 0, stream>>>(MEANV, CTXp);
        scatter_kernel<<<dim3(64, NTOP), 64, 0, stream>>>(UPD, MTOP, CTXp);

        // ---- attention out-projection ----
        split_kernel<<<(ROWS * DM / 4 + 255) / 256, 256, 0, stream>>>(CTXp, Ah, Al, ROWS * DM / 4);
        split_kernel<<<(DM * DM / 4 + 255) / 256, 256, 0, stream>>>(Wo_l, WhA, WlA, DM * DM / 4);
        mfma_gemm<64, 0><<<dim3(ROWS / 128, DM / 64), 256, 0, stream>>>(
            Ah, Al, WhA, WlA, bo_l, NXp, nullptr, nullptr, ROWS, DM, DM);
        add_ln_kernel<<<ROWS, 256, 0, stream>>>(X, NXp, g1_l, b1_l, X1p);

        // ---- FFN (2 chunks of 4096 rows) ----
        split_kernel<<<(ROWS * DM / 4 + 255) / 256, 256, 0, stream>>>(X1p, Ah, Al, ROWS * DM / 4);
        split_kernel<<<(DFF * DM / 4 + 255) / 256, 256, 0, stream>>>(c1w_l, WhA, WlA, DFF * DM / 4);
        split_kernel<<<(DM * DFF / 4 + 255) / 256, 256, 0, stream>>>(c2w_l, WhB, WlB, DM * DFF / 4);
        for (int mc = 0; mc < 2; ++mc) {
            size_t aoff = (size_t)mc * 4096 * DM;
            mfma_gemm<128, 2><<<dim3(4096 / 128, DFF / 128), 256, 0, stream>>>(
                Ah + aoff, Al + aoff, WhA, WlA, c1b_l, nullptr, Yh, Yl, 4096, DFF, DM);
            mfma_gemm<64, 0><<<dim3(4096 / 128, DM / 64), 256, 0, stream>>>(
                Yh, Yl, WhB, WlB, c2b_l, NXp + aoff, nullptr, nullptr, 4096, DM, DFF);
        }
        add_ln_kernel<<<ROWS, 256, 0, stream>>>(X1p, NXp, g2_l, b2_l, X);
    }

    final_kernel<<<ROWS, 256, 0, stream>>>(X, gf, bf, x_mark_enc, CTXp);
    proj1_kernel<<<dim3(40, 16), 256, 0, stream>>>(CTXp, proj_w, PART);
    proj2_kernel<<<1, 64, 0, stream>>>(PART, proj_b, out);
}

// Round 4
// 2211.960 us; speedup vs baseline: 1.8104x; 1.1642x over previous
//
#include <hip/hip_runtime.h>
#include <hip/hip_bf16.h>
#include <stdint.h>

// ---------------------------------------------------------------------------
// Informer encoder forward (B=8,S=1024,D=512,H=8,Dh=64,FF=2048,3 layers)
// Round 4: flash-style single-pass attention per (b,h); GEMM BK=64 (half the
// barriers); activation hi/lo splits fused into producer epilogues.
// ---------------------------------------------------------------------------

#define SQ 1024
#define DM 512
#define NH 8
#define DH 64
#define DFF 2048
#define NTOP 35
#define ROWS 8192            // B*S
#define QKVD 1536            // fused Q|K|V row stride
#define EPSF 1e-5f

typedef __attribute__((ext_vector_type(8))) short bf16x8;
typedef __attribute__((ext_vector_type(4))) float f32x4;

__device__ __forceinline__ void gload_lds16(const void* g, void* l) {
    __builtin_amdgcn_global_load_lds((const __attribute__((address_space(1))) void*)g,
                                     (__attribute__((address_space(3))) void*)l, 16, 0, 0);
}

__device__ inline float gelu_f(float v) {
    return 0.5f * v * (1.0f + erff(v * 0.7071067811865476f));
}

__device__ __forceinline__ void split_hl(float v, __hip_bfloat16& h, __hip_bfloat16& l) {
    h = __float2bfloat16(v);
    l = __float2bfloat16(v - __bfloat162float(h));
}

// ---------------- Threefry-2x32 (exact JAX PRNG) ---------------------------
__device__ inline void tf_round(uint32_t& x0, uint32_t& x1, int r) {
    x0 += x1;
    x1 = (x1 << r) | (x1 >> (32 - r));
    x1 ^= x0;
}
__device__ inline uint2 tf2x32(uint32_t k0, uint32_t k1, uint32_t x0, uint32_t x1) {
    uint32_t ks2 = k0 ^ k1 ^ 0x1BD11BDAu;
    x0 += k0; x1 += k1;
    tf_round(x0,x1,13); tf_round(x0,x1,15); tf_round(x0,x1,26); tf_round(x0,x1,6);
    x0 += k1; x1 += ks2 + 1u;
    tf_round(x0,x1,17); tf_round(x0,x1,29); tf_round(x0,x1,16); tf_round(x0,x1,24);
    x0 += ks2; x1 += k0 + 2u;
    tf_round(x0,x1,13); tf_round(x0,x1,15); tf_round(x0,x1,26); tf_round(x0,x1,6);
    x0 += k0; x1 += k1 + 3u;
    tf_round(x0,x1,17); tf_round(x0,x1,29); tf_round(x0,x1,16); tf_round(x0,x1,24);
    x0 += k1; x1 += ks2 + 4u;
    tf_round(x0,x1,13); tf_round(x0,x1,15); tf_round(x0,x1,26); tf_round(x0,x1,6);
    x0 += ks2; x1 += k0 + 5u;
    return make_uint2(x0, x1);
}

__global__ void idx_kernel(int lyr, int* __restrict__ idx) {
    int p = blockIdx.x * 256 + threadIdx.x;
    if (p >= SQ * NTOP) return;
    uint2 fk = tf2x32(0u, 42u, 0u, (uint32_t)lyr);
    uint2 a = tf2x32(fk.x, fk.y, 0u, 2u);
    uint2 bb = tf2x32(fk.x, fk.y, 1u, 3u);
    uint32_t k20 = a.y, k21 = bb.y;
    const int half = (SQ * NTOP) / 2;  // 17920
    uint32_t bits;
    if (p < half) bits = tf2x32(k20, k21, (uint32_t)p, (uint32_t)(half + p)).x;
    else          bits = tf2x32(k20, k21, (uint32_t)(p - half), (uint32_t)p).y;
    idx[p] = (int)(bits & 1023u);
}

// ------- conv1d token embedding + positional embedding (+fused split) ------
__global__ __launch_bounds__(256) void embed_kernel(const float* __restrict__ xe,
                                                    const float* __restrict__ tk,
                                                    float* __restrict__ X,
                                                    __hip_bfloat16* __restrict__ Xh,
                                                    __hip_bfloat16* __restrict__ Xl) {
    int row = blockIdx.x;            // b*1024+s
    int b = row >> 10, s = row & 1023;
    __shared__ float xv[9];
    int t = threadIdx.x;
    if (t < 9) {
        int w = t / 3, c = t % 3;
        int tt = s + w;
        int r = (tt == 0) ? 1023 : (tt <= 1024 ? tt - 1 : 0);
        xv[t] = xe[((size_t)b * SQ + r) * 3 + c];
    }
    __syncthreads();
    const float cdiv = 0.017988946039015984f;  // ln(10000)/512
    for (int d = t; d < DM; d += 256) {
        float acc = 0.f;
        #pragma unroll
        for (int wi = 0; wi < 9; ++wi) acc += xv[wi] * tk[wi * DM + d];
        int j2 = (d >> 1) * 2;
        float div = expf(-cdiv * (float)j2);
        float ang = (float)s * div;
        float pe = (d & 1) ? cosf(ang) : sinf(ang);
        float v = acc + pe;
        size_t o = (size_t)row * DM + d;
        X[o] = v;
        __hip_bfloat16 hb, lb; split_hl(v, hb, lb);
        Xh[o] = hb; Xl[o] = lb;
    }
}

// ---------------- fp32 -> bf16 hi/lo split (weights only now) --------------
__global__ __launch_bounds__(256) void split_kernel(const float* __restrict__ s,
                                                    __hip_bfloat16* __restrict__ h,
                                                    __hip_bfloat16* __restrict__ l,
                                                    int n4) {
    int i = blockIdx.x * 256 + threadIdx.x;
    if (i >= n4) return;
    float4 v = reinterpret_cast<const float4*>(s)[i];
    float vv[4] = {v.x, v.y, v.z, v.w};
    ushort hv[4], lv[4];
    #pragma unroll
    for (int j = 0; j < 4; ++j) {
        __hip_bfloat16 hb, lb; split_hl(vv[j], hb, lb);
        hv[j] = *reinterpret_cast<ushort*>(&hb);
        lv[j] = *reinterpret_cast<ushort*>(&lb);
    }
    reinterpret_cast<ushort4*>(h)[i] = make_ushort4(hv[0], hv[1], hv[2], hv[3]);
    reinterpret_cast<ushort4*>(l)[i] = make_ushort4(lv[0], lv[1], lv[2], lv[3]);
}

__global__ void catbias_kernel(const float* __restrict__ a, const float* __restrict__ b,
                               const float* __restrict__ c, float* __restrict__ o) {
    int t = threadIdx.x;   // 512
    o[t] = a[t]; o[512 + t] = b[t]; o[1024 + t] = c[t];
}

// ---------------- split-bf16 MFMA GEMM (BK=64) -----------------------------
// C(MxN) = (Ah+Al)(MxK) @ (Wh+Wl)(NxK)^T + bias; virtual K' = 3K with
// segments A:[h,l,h], W:[h,h,l]. BM=128, BN_ in {128,64}, BK=64, 256 thr.
// OUTMODE 0: fp32 C.  OUTMODE 2: gelu then split-bf16 (Oh,Ol).
template<int BN_, int OUTMODE>
__global__ __launch_bounds__(256) void mfma_gemm(
    const __hip_bfloat16* __restrict__ Ah, const __hip_bfloat16* __restrict__ Al,
    const __hip_bfloat16* __restrict__ Wh, const __hip_bfloat16* __restrict__ Wl,
    const float* __restrict__ bias,
    float* __restrict__ C,
    __hip_bfloat16* __restrict__ Oh, __hip_bfloat16* __restrict__ Ol,
    int M, int N, int K) {
    constexpr int NI = BN_ / 32;           // b-frags per wave
    __shared__ __hip_bfloat16 As[128 * 64];
    __shared__ __hip_bfloat16 Bs[BN_ * 64];
    const int t = threadIdx.x;
    const int lane = t & 63, w = t >> 6;
    const int wm = w >> 1, wn = w & 1;
    const int bm = blockIdx.x * 128, bn = blockIdx.y * BN_;
    const int r15 = lane & 15, kc = lane >> 4;
    f32x4 acc[4][NI];
    #pragma unroll
    for (int mi = 0; mi < 4; ++mi)
        #pragma unroll
        for (int ni = 0; ni < NI; ++ni)
            acc[mi][ni] = (f32x4){0.f, 0.f, 0.f, 0.f};

    const int KT = 3 * K;
    for (int kp = 0; kp < KT; kp += 64) {
        int seg = (kp >= 2 * K) ? 2 : ((kp >= K) ? 1 : 0);
        int k0 = kp - seg * K;
        const __hip_bfloat16* Ab = (seg == 1) ? Al : Ah;
        const __hip_bfloat16* Bb = (seg == 2) ? Wl : Wh;
        // stage A tile (128x64 bf16 = 16KB): 8 16B-slots per row, 3-bit XOR swz
        #pragma unroll
        for (int i = 0; i < 4; ++i) {
            int slot = i * 256 + t;
            int row = slot >> 3, cp = slot & 7;
            int cl = cp ^ (row & 7);
            gload_lds16(Ab + (size_t)(bm + row) * K + k0 + cl * 8, As + slot * 8);
        }
        #pragma unroll
        for (int i = 0; i < BN_ / 32; ++i) {
            int slot = i * 256 + t;
            int row = slot >> 3, cp = slot & 7;
            int cl = cp ^ (row & 7);
            gload_lds16(Bb + (size_t)(bn + row) * K + k0 + cl * 8, Bs + slot * 8);
        }
        __syncthreads();
        #pragma unroll
        for (int kk = 0; kk < 2; ++kk) {
            bf16x8 a[4], b[NI];
            #pragma unroll
            for (int mi = 0; mi < 4; ++mi) {
                int row = wm * 64 + mi * 16 + r15;
                int sl = ((kk << 2) | kc) ^ (row & 7);
                a[mi] = *reinterpret_cast<const bf16x8*>(As + row * 64 + sl * 8);
            }
            #pragma unroll
            for (int ni = 0; ni < NI; ++ni) {
                int row = wn * (BN_ / 2) + ni * 16 + r15;
                int sl = ((kk << 2) | kc) ^ (row & 7);
                b[ni] = *reinterpret_cast<const bf16x8*>(Bs + row * 64 + sl * 8);
            }
            #pragma unroll
            for (int mi = 0; mi < 4; ++mi)
                #pragma unroll
                for (int ni = 0; ni < NI; ++ni)
                    acc[mi][ni] = __builtin_amdgcn_mfma_f32_16x16x32_bf16(a[mi], b[ni], acc[mi][ni], 0, 0, 0);
        }
        __syncthreads();
    }

    const int rq = lane >> 4;
    #pragma unroll
    for (int mi = 0; mi < 4; ++mi) {
        #pragma unroll
        for (int ni = 0; ni < NI; ++ni) {
            int n = bn + wn * (BN_ / 2) + ni * 16 + r15;
            float bz = bias[n];
            #pragma unroll
            for (int r = 0; r < 4; ++r) {
                int m = bm + wm * 64 + mi * 16 + rq * 4 + r;
                float v = acc[mi][ni][r] + bz;
                if constexpr (OUTMODE == 0) {
                    C[(size_t)m * N + n] = v;
                } else {
                    float g = gelu_f(v);
                    __hip_bfloat16 hb, lb; split_hl(g, hb, lb);
                    Oh[(size_t)m * N + n] = hb;
                    Ol[(size_t)m * N + n] = lb;
                }
            }
        }
    }
}

// ---------------- sparsity measure M = max_s(QK_s) - sum_s(QK_s)/L ---------
__global__ __launch_bounds__(128) void mscore_kernel(const float* __restrict__ QKV,
                                                     const int* __restrict__ idx,
                                                     float* __restrict__ Mv) {
    int bh = blockIdx.x;                       // 64
    int l = blockIdx.y * 128 + threadIdx.x;    // 0..1023
    int b = bh >> 3, h = bh & 7;
    const float4* q = reinterpret_cast<const float4*>(QKV + ((size_t)(b * SQ + l)) * QKVD + h * DH);
    float4 qr[16];
    #pragma unroll
    for (int i = 0; i < 16; ++i) qr[i] = q[i];
    float mx = -INFINITY, sm = 0.f;
    for (int s = 0; s < NTOP; ++s) {
        int ki = idx[l * NTOP + s];
        const float4* kr = reinterpret_cast<const float4*>(QKV + ((size_t)(b * SQ + ki)) * QKVD + DM + h * DH);
        float d = 0.f;
        #pragma unroll
        for (int i = 0; i < 16; ++i) {
            float4 kv = kr[i];
            d += qr[i].x * kv.x + qr[i].y * kv.y + qr[i].z * kv.z + qr[i].w * kv.w;
        }
        mx = fmaxf(mx, d);
        sm += d;
    }
    Mv[bh * SQ + l] = mx - sm * (1.0f / (float)SQ);
}

// ---------------- top-35 argmax selection per (b,h) ------------------------
__global__ __launch_bounds__(256) void topk_kernel(const float* __restrict__ Mv,
                                                   int* __restrict__ Mtop) {
    int bh = blockIdx.x;
    __shared__ float vals[SQ];
    __shared__ float rv[256];
    __shared__ int ri[256];
    int t = threadIdx.x;
    for (int i = t; i < SQ; i += 256) vals[i] = Mv[bh * SQ + i];
    __syncthreads();
    for (int u = 0; u < NTOP; ++u) {
        float bvv = -INFINITY; int bi = 0x7fffffff;
        for (int i = t; i < SQ; i += 256) {
            float v = vals[i];
            if (v > bvv) { bvv = v; bi = i; }
        }
        rv[t] = bvv; ri[t] = bi;
        __syncthreads();
        for (int s = 128; s > 0; s >>= 1) {
            if (t < s) {
                if (rv[t + s] > rv[t] || (rv[t + s] == rv[t] && ri[t + s] < ri[t])) {
                    rv[t] = rv[t + s]; ri[t] = ri[t + s];
                }
            }
            __syncthreads();
        }
        if (t == 0) { Mtop[bh * NTOP + u] = ri[0]; vals[ri[0]] = -INFINITY; }
        __syncthreads();
    }
}

// ------ flash-style attention: one block per (b,h), all 35 queries ---------
__global__ __launch_bounds__(512) void attn2_kernel(const float* __restrict__ QKV,
                                                    const int* __restrict__ Mtop,
                                                    float* __restrict__ upd) {
    __shared__ float Qs[NTOP][68];
    __shared__ float Kt[64][68];
    __shared__ float Vt[64][68];
    __shared__ float St[NTOP][64];
    __shared__ float mS[NTOP], lS[NTOP], fS[NTOP];
    __shared__ int qidx[NTOP];
    int bh = blockIdx.x;
    int b = bh >> 3, h = bh & 7;
    int t = threadIdx.x, w = t >> 6, lane = t & 63;
    if (t < NTOP) { qidx[t] = Mtop[bh * NTOP + t]; mS[t] = -INFINITY; lS[t] = 0.f; }
    __syncthreads();
    for (int u = w; u < NTOP; u += 8)
        Qs[u][lane] = QKV[((size_t)(b * SQ + qidx[u])) * QKVD + h * DH + lane];
    float a_acc[5] = {0.f, 0.f, 0.f, 0.f, 0.f};
    __syncthreads();
    for (int tk = 0; tk < 16; ++tk) {
        // load K/V tile (64 keys x 64 dims)
        #pragma unroll
        for (int i = 0; i < 2; ++i) {
            int idx4 = i * 512 + t;            // 0..1023
            int kr = idx4 >> 4, c4 = (idx4 & 15) << 2;
            const float* kp = QKV + ((size_t)(b * SQ + tk * 64 + kr)) * QKVD + DM + h * DH + c4;
            *reinterpret_cast<float4*>(&Kt[kr][c4]) = *reinterpret_cast<const float4*>(kp);
            *reinterpret_cast<float4*>(&Vt[kr][c4]) = *reinterpret_cast<const float4*>(kp + DM);
        }
        __syncthreads();
        // scores: wave w owns u = w+8j; lane = key within tile
        float sv[5] = {0.f, 0.f, 0.f, 0.f, 0.f};
        #pragma unroll
        for (int d4 = 0; d4 < 16; ++d4) {
            float4 kv = *reinterpret_cast<const float4*>(&Kt[lane][d4 << 2]);
            #pragma unroll
            for (int j = 0; j < 5; ++j) {
                int u = w + 8 * j;
                if (u < NTOP) {
                    float4 qv = *reinterpret_cast<const float4*>(&Qs[u][d4 << 2]);
                    sv[j] += qv.x * kv.x + qv.y * kv.y + qv.z * kv.z + qv.w * kv.w;
                }
            }
        }
        #pragma unroll
        for (int j = 0; j < 5; ++j) {
            int u = w + 8 * j;
            if (u < NTOP) {
                float s = sv[j] * 0.125f;
                float mx = s;
                #pragma unroll
                for (int off = 32; off; off >>= 1) mx = fmaxf(mx, __shfl_xor(mx, off));
                float m_old = mS[u];
                float m_new = fmaxf(m_old, mx);
                float e = expf(s - m_new);
                float sum = e;
                #pragma unroll
                for (int off = 32; off; off >>= 1) sum += __shfl_xor(sum, off);
                St[u][lane] = e;
                if (lane == 0) {
                    float f = expf(m_old - m_new);
                    fS[u] = f;
                    lS[u] = lS[u] * f + sum;
                    mS[u] = m_new;
                }
            }
        }
        __syncthreads();
        // PV: thread (w, lane=d) accumulates its u's
        #pragma unroll
        for (int j = 0; j < 5; ++j) {
            int u = w + 8 * j;
            if (u < NTOP) {
                float acc = a_acc[j] * fS[u];
                for (int k = 0; k < 64; ++k)
                    acc += St[u][k] * Vt[k][lane];
                a_acc[j] = acc;
            }
        }
        __syncthreads();
    }
    #pragma unroll
    for (int j = 0; j < 5; ++j) {
        int u = w + 8 * j;
        if (u < NTOP)
            upd[((size_t)bh * NTOP + u) * DH + lane] = a_acc[j] / lS[u];
    }
}

// ---------------- V mean over sequence per (b,h,dh) ------------------------
__global__ __launch_bounds__(256) void meanv_kernel(const float* __restrict__ QKV,
                                                    float* __restrict__ meanV) {
    int bh = blockIdx.x;
    int t = threadIdx.x;
    int b = bh >> 3, h = bh & 7;
    int dh = t & 63, chunk = t >> 6;
    float acc = 0.f;
    for (int s = chunk * 256; s < chunk * 256 + 256; ++s)
        acc += QKV[((size_t)(b * SQ + s)) * QKVD + 2 * DM + h * DH + dh];
    __shared__ float red[256];
    red[t] = acc; __syncthreads();
    if (t < 64)
        meanV[bh * DH + dh] = (red[t] + red[64 + t] + red[128 + t] + red[192 + t]) * (1.0f / (float)SQ);
}

// ------- build context directly as bf16 hi/lo: broadcast + scatter ---------
__global__ void ctxfill2_kernel(const float* __restrict__ meanV,
                                __hip_bfloat16* __restrict__ ch,
                                __hip_bfloat16* __restrict__ cl) {
    int n = blockIdx.x * 256 + threadIdx.x;   // 0 .. 4194303
    int d = n & 511;
    int row = n >> 9;
    int b = row >> 10;
    float v = meanV[((b << 3) + (d >> 6)) * DH + (d & 63)];
    __hip_bfloat16 hb, lb; split_hl(v, hb, lb);
    ch[n] = hb; cl[n] = lb;
}

__global__ void scatter2_kernel(const float* __restrict__ upd, const int* __restrict__ Mtop,
                                __hip_bfloat16* __restrict__ ch,
                                __hip_bfloat16* __restrict__ cl) {
    int bh = blockIdx.x, u = blockIdx.y;
    int t = threadIdx.x;   // 64
    int b = bh >> 3, h = bh & 7;
    int l = Mtop[bh * NTOP + u];
    float v = upd[((size_t)bh * NTOP + u) * DH + t];
    size_t o = ((size_t)(b * SQ + l)) * DM + h * DH + t;
    __hip_bfloat16 hb, lb; split_hl(v, hb, lb);
    ch[o] = hb; cl[o] = lb;
}

// ---------------- residual add + LayerNorm (+fused split) ------------------
__global__ __launch_bounds__(256) void add_ln_kernel(const float* __restrict__ Av,
                                                     const float* __restrict__ Bv,
                                                     const float* __restrict__ g,
                                                     const float* __restrict__ be,
                                                     float* __restrict__ out,
                                                     __hip_bfloat16* __restrict__ oh,
                                                     __hip_bfloat16* __restrict__ ol) {
    int row = blockIdx.x;
    int t = threadIdx.x;
    size_t base = (size_t)row * DM;
    float v0 = Av[base + t] + Bv[base + t];
    float v1 = Av[base + 256 + t] + Bv[base + 256 + t];
    __shared__ float r1[256], r2[256];
    r1[t] = v0 + v1; r2[t] = v0 * v0 + v1 * v1;
    __syncthreads();
    for (int s = 128; s > 0; s >>= 1) {
        if (t < s) { r1[t] += r1[t + s]; r2[t] += r2[t + s]; }
        __syncthreads();
    }
    float mu = r1[0] * (1.0f / (float)DM);
    float var = r2[0] * (1.0f / (float)DM) - mu * mu;
    float rs = rsqrtf(var + EPSF);
    float o0 = (v0 - mu) * rs * g[t] + be[t];
    float o1 = (v1 - mu) * rs * g[t + 256] + be[t + 256];
    out[base + t] = o0;
    out[base + 256 + t] = o1;
    __hip_bfloat16 hb, lb;
    split_hl(o0, hb, lb); oh[base + t] = hb; ol[base + t] = lb;
    split_hl(o1, hb, lb); oh[base + 256 + t] = hb; ol[base + 256 + t] = lb;
}

// ---------------- final LN + GELU + mask -----------------------------------
__global__ __launch_bounds__(256) void final_kernel(const float* __restrict__ X,
                                                    const float* __restrict__ g,
                                                    const float* __restrict__ be,
                                                    const float* __restrict__ mark,
                                                    float* __restrict__ act) {
    int row = blockIdx.x;
    int t = threadIdx.x;
    size_t base = (size_t)row * DM;
    float v0 = X[base + t];
    float v1 = X[base + 256 + t];
    __shared__ float r1[256], r2[256];
    r1[t] = v0 + v1; r2[t] = v0 * v0 + v1 * v1;
    __syncthreads();
    for (int s = 128; s > 0; s >>= 1) {
        if (t < s) { r1[t] += r1[t + s]; r2[t] += r2[t + s]; }
        __syncthreads();
    }
    float mu = r1[0] * (1.0f / (float)DM);
    float var = r2[0] * (1.0f / (float)DM) - mu * mu;
    float rs = rsqrtf(var + EPSF);
    float mk = mark[row];
    float a0 = (v0 - mu) * rs * g[t] + be[t];
    float a1 = (v1 - mu) * rs * g[t + 256] + be[t + 256];
    act[base + t] = gelu_f(a0) * mk;
    act[base + 256 + t] = gelu_f(a1) * mk;
}

// ---------------- final projection: two-stage ------------------------------
__global__ __launch_bounds__(256) void proj1_kernel(const float* __restrict__ act,
                                                    const float* __restrict__ pw,
                                                    float* __restrict__ part) {
    int bc = blockIdx.x;      // 40
    int sg = blockIdx.y;      // 16
    int b = bc / 5, c = bc % 5;
    const float4* a = reinterpret_cast<const float4*>(act + (size_t)b * (SQ * DM) + sg * 32768);
    const float4* w = reinterpret_cast<const float4*>(pw + (size_t)c * (SQ * DM) + sg * 32768);
    float s = 0.f;
    for (int i = threadIdx.x; i < 8192; i += 256) {
        float4 av = a[i], wv = w[i];
        s += av.x * wv.x + av.y * wv.y + av.z * wv.z + av.w * wv.w;
    }
    __shared__ float red[256];
    red[threadIdx.x] = s; __syncthreads();
    for (int sft = 128; sft > 0; sft >>= 1) {
        if (threadIdx.x < sft) red[threadIdx.x] += red[threadIdx.x + sft];
        __syncthreads();
    }
    if (threadIdx.x == 0) part[bc * 16 + sg] = red[0];
}

__global__ void proj2_kernel(const float* __restrict__ part, const float* __restrict__ pb,
                             float* __restrict__ out) {
    int t = threadIdx.x;  // 64
    if (t < 40) {
        float s = 0.f;
        #pragma unroll
        for (int i = 0; i < 16; ++i) s += part[t * 16 + i];
        out[t] = s + pb[t % 5];
    }
}

// ---------------------------------------------------------------------------
extern "C" void kernel_launch(void* const* d_in, const int* in_sizes, int n_in,
                              void* d_out, int out_size, void* d_ws, size_t ws_size,
                              hipStream_t stream) {
    (void)in_sizes; (void)n_in; (void)out_size; (void)ws_size;

    const float* x_enc      = (const float*)d_in[0];
    const float* x_mark_enc = (const float*)d_in[1];
    const float* token_k    = (const float*)d_in[2];
    const float* Wq = (const float*)d_in[3];
    const float* bq = (const float*)d_in[4];
    const float* Wk = (const float*)d_in[5];
    const float* bk = (const float*)d_in[6];
    const float* Wv = (const float*)d_in[7];
    const float* bv = (const float*)d_in[8];
    const float* Wo = (const float*)d_in[9];
    const float* bo = (const float*)d_in[10];
    const float* c1w = (const float*)d_in[11];
    const float* c1b = (const float*)d_in[12];
    const float* c2w = (const float*)d_in[13];
    const float* c2b = (const float*)d_in[14];
    const float* g1 = (const float*)d_in[15];
    const float* b1 = (const float*)d_in[16];
    const float* g2 = (const float*)d_in[17];
    const float* b2 = (const float*)d_in[18];
    const float* gf = (const float*)d_in[19];
    const float* bf = (const float*)d_in[20];
    const float* proj_w = (const float*)d_in[21];
    const float* proj_b = (const float*)d_in[22];
    float* out = (float*)d_out;

    const size_t MB = 1024 * 1024;
    char* wsb = (char*)d_ws;
    // fp32 regions
    float* X    = (float*)(wsb);                  // 0..16
    float* QKVp = (float*)(wsb + 16 * MB);        // 16..64 (8192x1536 fp32)
    // aliases inside the QKV region (QKV dead once meanv has run):
    __hip_bfloat16* CTXh = (__hip_bfloat16*)(wsb + 16 * MB);  // 16..24
    __hip_bfloat16* CTXl = (__hip_bfloat16*)(wsb + 24 * MB);  // 24..32
    __hip_bfloat16* Yh   = (__hip_bfloat16*)(wsb + 32 * MB);  // 32..48
    __hip_bfloat16* Yl   = (__hip_bfloat16*)(wsb + 48 * MB);  // 48..64
    float* X1p  = (float*)(wsb + 64 * MB);        // 64..80
    float* NXp  = (float*)(wsb + 80 * MB);        // 80..96
    __hip_bfloat16* Xh  = (__hip_bfloat16*)(wsb + 96 * MB);   // 96..104
    __hip_bfloat16* Xl  = (__hip_bfloat16*)(wsb + 104 * MB);  // 104..112
    __hip_bfloat16* X1h = (__hip_bfloat16*)(wsb + 112 * MB);  // 112..120
    __hip_bfloat16* X1l = (__hip_bfloat16*)(wsb + 120 * MB);  // 120..128
    __hip_bfloat16* WhA = (__hip_bfloat16*)(wsb + 128 * MB);  // 128..130
    __hip_bfloat16* WlA = (__hip_bfloat16*)(wsb + 130 * MB);  // 130..132
    __hip_bfloat16* WhB = (__hip_bfloat16*)(wsb + 132 * MB);  // 132..134
    __hip_bfloat16* WlB = (__hip_bfloat16*)(wsb + 134 * MB);  // 134..136
    float* biasC = (float*)(wsb + 136 * MB);
    char* smal  = wsb + 136 * MB + 65536;
    float* Mbuf  = (float*)(smal);                            // 256 KB
    int*   IDX   = (int*)(smal + 262144);                     // 140 KB
    int*   MTOP  = (int*)(smal + 262144 + 262144);            // 9 KB
    float* UPD   = (float*)(smal + 262144 + 262144 + 16384);  // 560 KB
    float* MEANV = (float*)(smal + 262144 + 262144 + 16384 + 1048576);
    float* PART  = (float*)(smal + 262144 + 262144 + 16384 + 1048576 + 65536);

    embed_kernel<<<ROWS, 256, 0, stream>>>(x_enc, token_k, X, Xh, Xl);

    for (int lyr = 0; lyr < 3; ++lyr) {
        const float* Wq_l = Wq + (size_t)lyr * DM * DM;
        const float* bq_l = bq + (size_t)lyr * DM;
        const float* Wk_l = Wk + (size_t)lyr * DM * DM;
        const float* bk_l = bk + (size_t)lyr * DM;
        const float* Wv_l = Wv + (size_t)lyr * DM * DM;
        const float* bv_l = bv + (size_t)lyr * DM;
        const float* Wo_l = Wo + (size_t)lyr * DM * DM;
        const float* bo_l = bo + (size_t)lyr * DM;
        const float* c1w_l = c1w + (size_t)lyr * DFF * DM;
        const float* c1b_l = c1b + (size_t)lyr * DFF;
        const float* c2w_l = c2w + (size_t)lyr * DM * DFF;
        const float* c2b_l = c2b + (size_t)lyr * DM;
        const float* g1_l = g1 + (size_t)lyr * DM;
        const float* b1_l = b1 + (size_t)lyr * DM;
        const float* g2_l = g2 + (size_t)lyr * DM;
        const float* b2_l = b2 + (size_t)lyr * DM;

        // ---- fused QKV projection (N=1536) ----
        split_kernel<<<(DM * DM / 4 + 255) / 256, 256, 0, stream>>>(Wq_l, WhA, WlA, DM * DM / 4);
        split_kernel<<<(DM * DM / 4 + 255) / 256, 256, 0, stream>>>(Wk_l, WhA + DM * DM, WlA + DM * DM, DM * DM / 4);
        split_kernel<<<(DM * DM / 4 + 255) / 256, 256, 0, stream>>>(Wv_l, WhA + 2 * DM * DM, WlA + 2 * DM * DM, DM * DM / 4);
        catbias_kernel<<<1, 512, 0, stream>>>(bq_l, bk_l, bv_l, biasC);
        mfma_gemm<128, 0><<<dim3(ROWS / 128, QKVD / 128), 256, 0, stream>>>(
            Xh, Xl, WhA, WlA, biasC, QKVp, nullptr, nullptr, ROWS, QKVD, DM);

        // ---- ProbSparse attention ----
        idx_kernel<<<(SQ * NTOP + 255) / 256, 256, 0, stream>>>(lyr, IDX);
        mscore_kernel<<<dim3(64, 8), 128, 0, stream>>>(QKVp, IDX, Mbuf);
        topk_kernel<<<64, 256, 0, stream>>>(Mbuf, MTOP);
        attn2_kernel<<<64, 512, 0, stream>>>(QKVp, MTOP, UPD);
        meanv_kernel<<<64, 256, 0, stream>>>(QKVp, MEANV);
        // QKV fp32 is dead now; write context straight into its region as h/l
        ctxfill2_kernel<<<(ROWS * DM) / 256, 256, 0, stream>>>(MEANV, CTXh, CTXl);
        scatter2_kernel<<<dim3(64, NTOP), 64, 0, stream>>>(UPD, MTOP, CTXh, CTXl);

        // ---- attention out-projection ----
        split_kernel<<<(DM * DM / 4 + 255) / 256, 256, 0, stream>>>(Wo_l, WhB, WlB, DM * DM / 4);
        mfma_gemm<64, 0><<<dim3(ROWS / 128, DM / 64), 256, 0, stream>>>(
            CTXh, CTXl, WhB, WlB, bo_l, NXp, nullptr, nullptr, ROWS, DM, DM);
        add_ln_kernel<<<ROWS, 256, 0, stream>>>(X, NXp, g1_l, b1_l, X1p, X1h, X1l);

        // ---- FFN (2 chunks of 4096 rows) ----
        split_kernel<<<(DFF * DM / 4 + 255) / 256, 256, 0, stream>>>(c1w_l, WhA, WlA, DFF * DM / 4);
        split_kernel<<<(DM * DFF / 4 + 255) / 256, 256, 0, stream>>>(c2w_l, WhB, WlB, DM * DFF / 4);
        for (int mc = 0; mc < 2; ++mc) {
            size_t aoff = (size_t)mc * 4096 * DM;
            mfma_gemm<128, 2><<<dim3(4096 / 128, DFF / 128), 256, 0, stream>>>(
                X1h + aoff, X1l + aoff, WhA, WlA, c1b_l, nullptr, Yh, Yl, 4096, DFF, DM);
            mfma_gemm<64, 0><<<dim3(4096 / 128, DM / 64), 256, 0, stream>>>(
                Yh, Yl, WhB, WlB, c2b_l, NXp + aoff, nullptr, nullptr, 4096, DM, DFF);
        }
        add_ln_kernel<<<ROWS, 256, 0, stream>>>(X1p, NXp, g2_l, b2_l, X, Xh, Xl);
    }

    final_kernel<<<ROWS, 256, 0, stream>>>(X, gf, bf, x_mark_enc, (float*)QKVp);
    proj1_kernel<<<dim3(40, 16), 256, 0, stream>>>((float*)QKVp, proj_w, PART);
    proj2_kernel<<<1, 64, 0, stream>>>(PART, proj_b, out);
}

// Round 5
// 1752.697 us; speedup vs baseline: 2.2848x; 1.2620x over previous
//
#include <hip/hip_runtime.h>
#include <hip/hip_bf16.h>
#include <stdint.h>

// ---------------------------------------------------------------------------
// Informer encoder forward (B=8,S=1024,D=512,H=8,Dh=64,FF=2048,3 layers)
// Round 5: split-K flash attention (512 blocks + combine), split-S mscore
// (2048 blocks, combine folded into topk), unchunked FFN.
// ---------------------------------------------------------------------------

#define SQ 1024
#define DM 512
#define NH 8
#define DH 64
#define DFF 2048
#define NTOP 35
#define ROWS 8192            // B*S
#define QKVD 1536            // fused Q|K|V row stride
#define EPSF 1e-5f
#define KSPLIT 8             // attention key splits
#define SSPLIT 4             // mscore sample splits

typedef __attribute__((ext_vector_type(8))) short bf16x8;
typedef __attribute__((ext_vector_type(4))) float f32x4;

__device__ __forceinline__ void gload_lds16(const void* g, void* l) {
    __builtin_amdgcn_global_load_lds((const __attribute__((address_space(1))) void*)g,
                                     (__attribute__((address_space(3))) void*)l, 16, 0, 0);
}

__device__ inline float gelu_f(float v) {
    return 0.5f * v * (1.0f + erff(v * 0.7071067811865476f));
}

__device__ __forceinline__ void split_hl(float v, __hip_bfloat16& h, __hip_bfloat16& l) {
    h = __float2bfloat16(v);
    l = __float2bfloat16(v - __bfloat162float(h));
}

// ---------------- Threefry-2x32 (exact JAX PRNG) ---------------------------
__device__ inline void tf_round(uint32_t& x0, uint32_t& x1, int r) {
    x0 += x1;
    x1 = (x1 << r) | (x1 >> (32 - r));
    x1 ^= x0;
}
__device__ inline uint2 tf2x32(uint32_t k0, uint32_t k1, uint32_t x0, uint32_t x1) {
    uint32_t ks2 = k0 ^ k1 ^ 0x1BD11BDAu;
    x0 += k0; x1 += k1;
    tf_round(x0,x1,13); tf_round(x0,x1,15); tf_round(x0,x1,26); tf_round(x0,x1,6);
    x0 += k1; x1 += ks2 + 1u;
    tf_round(x0,x1,17); tf_round(x0,x1,29); tf_round(x0,x1,16); tf_round(x0,x1,24);
    x0 += ks2; x1 += k0 + 2u;
    tf_round(x0,x1,13); tf_round(x0,x1,15); tf_round(x0,x1,26); tf_round(x0,x1,6);
    x0 += k0; x1 += k1 + 3u;
    tf_round(x0,x1,17); tf_round(x0,x1,29); tf_round(x0,x1,16); tf_round(x0,x1,24);
    x0 += k1; x1 += ks2 + 4u;
    tf_round(x0,x1,13); tf_round(x0,x1,15); tf_round(x0,x1,26); tf_round(x0,x1,6);
    x0 += ks2; x1 += k0 + 5u;
    return make_uint2(x0, x1);
}

__global__ void idx_kernel(int lyr, int* __restrict__ idx) {
    int p = blockIdx.x * 256 + threadIdx.x;
    if (p >= SQ * NTOP) return;
    uint2 fk = tf2x32(0u, 42u, 0u, (uint32_t)lyr);
    uint2 a = tf2x32(fk.x, fk.y, 0u, 2u);
    uint2 bb = tf2x32(fk.x, fk.y, 1u, 3u);
    uint32_t k20 = a.y, k21 = bb.y;
    const int half = (SQ * NTOP) / 2;  // 17920
    uint32_t bits;
    if (p < half) bits = tf2x32(k20, k21, (uint32_t)p, (uint32_t)(half + p)).x;
    else          bits = tf2x32(k20, k21, (uint32_t)(p - half), (uint32_t)p).y;
    idx[p] = (int)(bits & 1023u);
}

// ------- conv1d token embedding + positional embedding (+fused split) ------
__global__ __launch_bounds__(256) void embed_kernel(const float* __restrict__ xe,
                                                    const float* __restrict__ tk,
                                                    float* __restrict__ X,
                                                    __hip_bfloat16* __restrict__ Xh,
                                                    __hip_bfloat16* __restrict__ Xl) {
    int row = blockIdx.x;            // b*1024+s
    int b = row >> 10, s = row & 1023;
    __shared__ float xv[9];
    int t = threadIdx.x;
    if (t < 9) {
        int w = t / 3, c = t % 3;
        int tt = s + w;
        int r = (tt == 0) ? 1023 : (tt <= 1024 ? tt - 1 : 0);
        xv[t] = xe[((size_t)b * SQ + r) * 3 + c];
    }
    __syncthreads();
    const float cdiv = 0.017988946039015984f;  // ln(10000)/512
    for (int d = t; d < DM; d += 256) {
        float acc = 0.f;
        #pragma unroll
        for (int wi = 0; wi < 9; ++wi) acc += xv[wi] * tk[wi * DM + d];
        int j2 = (d >> 1) * 2;
        float div = expf(-cdiv * (float)j2);
        float ang = (float)s * div;
        float pe = (d & 1) ? cosf(ang) : sinf(ang);
        float v = acc + pe;
        size_t o = (size_t)row * DM + d;
        X[o] = v;
        __hip_bfloat16 hb, lb; split_hl(v, hb, lb);
        Xh[o] = hb; Xl[o] = lb;
    }
}

// ---------------- fp32 -> bf16 hi/lo split (weights only) ------------------
__global__ __launch_bounds__(256) void split_kernel(const float* __restrict__ s,
                                                    __hip_bfloat16* __restrict__ h,
                                                    __hip_bfloat16* __restrict__ l,
                                                    int n4) {
    int i = blockIdx.x * 256 + threadIdx.x;
    if (i >= n4) return;
    float4 v = reinterpret_cast<const float4*>(s)[i];
    float vv[4] = {v.x, v.y, v.z, v.w};
    ushort hv[4], lv[4];
    #pragma unroll
    for (int j = 0; j < 4; ++j) {
        __hip_bfloat16 hb, lb; split_hl(vv[j], hb, lb);
        hv[j] = *reinterpret_cast<ushort*>(&hb);
        lv[j] = *reinterpret_cast<ushort*>(&lb);
    }
    reinterpret_cast<ushort4*>(h)[i] = make_ushort4(hv[0], hv[1], hv[2], hv[3]);
    reinterpret_cast<ushort4*>(l)[i] = make_ushort4(lv[0], lv[1], lv[2], lv[3]);
}

__global__ void catbias_kernel(const float* __restrict__ a, const float* __restrict__ b,
                               const float* __restrict__ c, float* __restrict__ o) {
    int t = threadIdx.x;   // 512
    o[t] = a[t]; o[512 + t] = b[t]; o[1024 + t] = c[t];
}

// ---------------- split-bf16 MFMA GEMM (BK=64) -----------------------------
template<int BN_, int OUTMODE>
__global__ __launch_bounds__(256) void mfma_gemm(
    const __hip_bfloat16* __restrict__ Ah, const __hip_bfloat16* __restrict__ Al,
    const __hip_bfloat16* __restrict__ Wh, const __hip_bfloat16* __restrict__ Wl,
    const float* __restrict__ bias,
    float* __restrict__ C,
    __hip_bfloat16* __restrict__ Oh, __hip_bfloat16* __restrict__ Ol,
    int M, int N, int K) {
    constexpr int NI = BN_ / 32;           // b-frags per wave
    __shared__ __hip_bfloat16 As[128 * 64];
    __shared__ __hip_bfloat16 Bs[BN_ * 64];
    const int t = threadIdx.x;
    const int lane = t & 63, w = t >> 6;
    const int wm = w >> 1, wn = w & 1;
    const int bm = blockIdx.x * 128, bn = blockIdx.y * BN_;
    const int r15 = lane & 15, kc = lane >> 4;
    f32x4 acc[4][NI];
    #pragma unroll
    for (int mi = 0; mi < 4; ++mi)
        #pragma unroll
        for (int ni = 0; ni < NI; ++ni)
            acc[mi][ni] = (f32x4){0.f, 0.f, 0.f, 0.f};

    const int KT = 3 * K;
    for (int kp = 0; kp < KT; kp += 64) {
        int seg = (kp >= 2 * K) ? 2 : ((kp >= K) ? 1 : 0);
        int k0 = kp - seg * K;
        const __hip_bfloat16* Ab = (seg == 1) ? Al : Ah;
        const __hip_bfloat16* Bb = (seg == 2) ? Wl : Wh;
        #pragma unroll
        for (int i = 0; i < 4; ++i) {
            int slot = i * 256 + t;
            int row = slot >> 3, cp = slot & 7;
            int cl = cp ^ (row & 7);
            gload_lds16(Ab + (size_t)(bm + row) * K + k0 + cl * 8, As + slot * 8);
        }
        #pragma unroll
        for (int i = 0; i < BN_ / 32; ++i) {
            int slot = i * 256 + t;
            int row = slot >> 3, cp = slot & 7;
            int cl = cp ^ (row & 7);
            gload_lds16(Bb + (size_t)(bn + row) * K + k0 + cl * 8, Bs + slot * 8);
        }
        __syncthreads();
        #pragma unroll
        for (int kk = 0; kk < 2; ++kk) {
            bf16x8 a[4], b[NI];
            #pragma unroll
            for (int mi = 0; mi < 4; ++mi) {
                int row = wm * 64 + mi * 16 + r15;
                int sl = ((kk << 2) | kc) ^ (row & 7);
                a[mi] = *reinterpret_cast<const bf16x8*>(As + row * 64 + sl * 8);
            }
            #pragma unroll
            for (int ni = 0; ni < NI; ++ni) {
                int row = wn * (BN_ / 2) + ni * 16 + r15;
                int sl = ((kk << 2) | kc) ^ (row & 7);
                b[ni] = *reinterpret_cast<const bf16x8*>(Bs + row * 64 + sl * 8);
            }
            #pragma unroll
            for (int mi = 0; mi < 4; ++mi)
                #pragma unroll
                for (int ni = 0; ni < NI; ++ni)
                    acc[mi][ni] = __builtin_amdgcn_mfma_f32_16x16x32_bf16(a[mi], b[ni], acc[mi][ni], 0, 0, 0);
        }
        __syncthreads();
    }

    const int rq = lane >> 4;
    #pragma unroll
    for (int mi = 0; mi < 4; ++mi) {
        #pragma unroll
        for (int ni = 0; ni < NI; ++ni) {
            int n = bn + wn * (BN_ / 2) + ni * 16 + r15;
            float bz = bias[n];
            #pragma unroll
            for (int r = 0; r < 4; ++r) {
                int m = bm + wm * 64 + mi * 16 + rq * 4 + r;
                float v = acc[mi][ni][r] + bz;
                if constexpr (OUTMODE == 0) {
                    C[(size_t)m * N + n] = v;
                } else {
                    float g = gelu_f(v);
                    __hip_bfloat16 hb, lb; split_hl(g, hb, lb);
                    Oh[(size_t)m * N + n] = hb;
                    Ol[(size_t)m * N + n] = lb;
                }
            }
        }
    }
}

// ------- sparsity measure partials: sample-chunked gather ------------------
__global__ __launch_bounds__(128) void mscore_part(const float* __restrict__ QKV,
                                                   const int* __restrict__ idx,
                                                   float* __restrict__ MX,
                                                   float* __restrict__ SM) {
    int bh = blockIdx.x;                       // 64
    int l = blockIdx.y * 128 + threadIdx.x;    // 0..1023
    int sc = blockIdx.z;                       // 0..3
    int b = bh >> 3, h = bh & 7;
    const float4* q = reinterpret_cast<const float4*>(QKV + ((size_t)(b * SQ + l)) * QKVD + h * DH);
    float4 qr[16];
    #pragma unroll
    for (int i = 0; i < 16; ++i) qr[i] = q[i];
    int s0 = sc * 9;
    int s1 = (s0 + 9 < NTOP) ? s0 + 9 : NTOP;
    float mx = -INFINITY, sm = 0.f;
    for (int s = s0; s < s1; ++s) {
        int ki = idx[l * NTOP + s];
        const float4* kr = reinterpret_cast<const float4*>(QKV + ((size_t)(b * SQ + ki)) * QKVD + DM + h * DH);
        float d = 0.f;
        #pragma unroll
        for (int i = 0; i < 16; ++i) {
            float4 kv = kr[i];
            d += qr[i].x * kv.x + qr[i].y * kv.y + qr[i].z * kv.z + qr[i].w * kv.w;
        }
        mx = fmaxf(mx, d);
        sm += d;
    }
    size_t o = ((size_t)(bh * SSPLIT + sc) << 10) + l;
    MX[o] = mx; SM[o] = sm;
}

// ---------------- top-35 argmax (combines mscore partials) -----------------
__global__ __launch_bounds__(256) void topk_kernel(const float* __restrict__ MX,
                                                   const float* __restrict__ SM,
                                                   int* __restrict__ Mtop) {
    int bh = blockIdx.x;
    __shared__ float vals[SQ];
    __shared__ float rv[256];
    __shared__ int ri[256];
    int t = threadIdx.x;
    for (int i = t; i < SQ; i += 256) {
        float mx = -INFINITY, sm = 0.f;
        #pragma unroll
        for (int sc = 0; sc < SSPLIT; ++sc) {
            size_t o = ((size_t)(bh * SSPLIT + sc) << 10) + i;
            mx = fmaxf(mx, MX[o]);
            sm += SM[o];
        }
        vals[i] = mx - sm * (1.0f / (float)SQ);
    }
    __syncthreads();
    for (int u = 0; u < NTOP; ++u) {
        float bvv = -INFINITY; int bi = 0x7fffffff;
        for (int i = t; i < SQ; i += 256) {
            float v = vals[i];
            if (v > bvv) { bvv = v; bi = i; }
        }
        rv[t] = bvv; ri[t] = bi;
        __syncthreads();
        for (int s = 128; s > 0; s >>= 1) {
            if (t < s) {
                if (rv[t + s] > rv[t] || (rv[t + s] == rv[t] && ri[t + s] < ri[t])) {
                    rv[t] = rv[t + s]; ri[t] = ri[t + s];
                }
            }
            __syncthreads();
        }
        if (t == 0) { Mtop[bh * NTOP + u] = ri[0]; vals[ri[0]] = -INFINITY; }
        __syncthreads();
    }
}

// ------ split-K flash attention partials: 8 splits x 64 bh -----------------
__global__ __launch_bounds__(512) void attn_part(const float* __restrict__ QKV,
                                                 const int* __restrict__ Mtop,
                                                 float* __restrict__ PACC,
                                                 float* __restrict__ PM,
                                                 float* __restrict__ PL) {
    __shared__ float Qs[NTOP][68];
    __shared__ float Kt[64][68];
    __shared__ float Vt[64][68];
    __shared__ float St[NTOP][64];
    __shared__ float mS[NTOP], lS[NTOP], fS[NTOP];
    __shared__ int qidx[NTOP];
    int bh = blockIdx.x, ks = blockIdx.y;
    int b = bh >> 3, h = bh & 7;
    int t = threadIdx.x, w = t >> 6, lane = t & 63;
    if (t < NTOP) { qidx[t] = Mtop[bh * NTOP + t]; mS[t] = -INFINITY; lS[t] = 0.f; }
    __syncthreads();
    for (int u = w; u < NTOP; u += 8)
        Qs[u][lane] = QKV[((size_t)(b * SQ + qidx[u])) * QKVD + h * DH + lane];
    float a_acc[5] = {0.f, 0.f, 0.f, 0.f, 0.f};
    __syncthreads();
    for (int tk = ks * 2; tk < ks * 2 + 2; ++tk) {
        #pragma unroll
        for (int i = 0; i < 2; ++i) {
            int idx4 = i * 512 + t;            // 0..1023
            int kr = idx4 >> 4, c4 = (idx4 & 15) << 2;
            const float* kp = QKV + ((size_t)(b * SQ + tk * 64 + kr)) * QKVD + DM + h * DH + c4;
            *reinterpret_cast<float4*>(&Kt[kr][c4]) = *reinterpret_cast<const float4*>(kp);
            *reinterpret_cast<float4*>(&Vt[kr][c4]) = *reinterpret_cast<const float4*>(kp + DM);
        }
        __syncthreads();
        float sv[5] = {0.f, 0.f, 0.f, 0.f, 0.f};
        #pragma unroll
        for (int d4 = 0; d4 < 16; ++d4) {
            float4 kv = *reinterpret_cast<const float4*>(&Kt[lane][d4 << 2]);
            #pragma unroll
            for (int j = 0; j < 5; ++j) {
                int u = w + 8 * j;
                if (u < NTOP) {
                    float4 qv = *reinterpret_cast<const float4*>(&Qs[u][d4 << 2]);
                    sv[j] += qv.x * kv.x + qv.y * kv.y + qv.z * kv.z + qv.w * kv.w;
                }
            }
        }
        #pragma unroll
        for (int j = 0; j < 5; ++j) {
            int u = w + 8 * j;
            if (u < NTOP) {
                float s = sv[j] * 0.125f;
                float mx = s;
                #pragma unroll
                for (int off = 32; off; off >>= 1) mx = fmaxf(mx, __shfl_xor(mx, off));
                float m_old = mS[u];
                float m_new = fmaxf(m_old, mx);
                float e = expf(s - m_new);
                float sum = e;
                #pragma unroll
                for (int off = 32; off; off >>= 1) sum += __shfl_xor(sum, off);
                St[u][lane] = e;
                if (lane == 0) {
                    float f = expf(m_old - m_new);
                    fS[u] = f;
                    lS[u] = lS[u] * f + sum;
                    mS[u] = m_new;
                }
            }
        }
        __syncthreads();
        #pragma unroll
        for (int j = 0; j < 5; ++j) {
            int u = w + 8 * j;
            if (u < NTOP) {
                float acc = a_acc[j] * fS[u];
                for (int k = 0; k < 64; ++k)
                    acc += St[u][k] * Vt[k][lane];
                a_acc[j] = acc;
            }
        }
        __syncthreads();
    }
    #pragma unroll
    for (int j = 0; j < 5; ++j) {
        int u = w + 8 * j;
        if (u < NTOP) {
            PACC[(((size_t)bh * KSPLIT + ks) * NTOP + u) * DH + lane] = a_acc[j];
            if (lane == 0) {
                PM[((size_t)bh * KSPLIT + ks) * NTOP + u] = mS[u];
                PL[((size_t)bh * KSPLIT + ks) * NTOP + u] = lS[u];
            }
        }
    }
}

// ---------------- combine attention partials -------------------------------
__global__ __launch_bounds__(512) void attn_comb(const float* __restrict__ PACC,
                                                 const float* __restrict__ PM,
                                                 const float* __restrict__ PL,
                                                 float* __restrict__ upd) {
    int bh = blockIdx.x;
    int t = threadIdx.x, w = t >> 6, lane = t & 63;
    #pragma unroll
    for (int j = 0; j < 5; ++j) {
        int u = w + 8 * j;
        if (u < NTOP) {
            float M = -INFINITY;
            #pragma unroll
            for (int i = 0; i < KSPLIT; ++i)
                M = fmaxf(M, PM[((size_t)bh * KSPLIT + i) * NTOP + u]);
            float lsum = 0.f, acc = 0.f;
            #pragma unroll
            for (int i = 0; i < KSPLIT; ++i) {
                float f = expf(PM[((size_t)bh * KSPLIT + i) * NTOP + u] - M);
                lsum += f * PL[((size_t)bh * KSPLIT + i) * NTOP + u];
                acc += f * PACC[(((size_t)bh * KSPLIT + i) * NTOP + u) * DH + lane];
            }
            upd[((size_t)bh * NTOP + u) * DH + lane] = acc / lsum;
        }
    }
}

// ---------------- V mean over sequence per (b,h,dh) ------------------------
__global__ __launch_bounds__(256) void meanv_kernel(const float* __restrict__ QKV,
                                                    float* __restrict__ meanV) {
    int bh = blockIdx.x;
    int t = threadIdx.x;
    int b = bh >> 3, h = bh & 7;
    int dh = t & 63, chunk = t >> 6;
    float acc = 0.f;
    for (int s = chunk * 256; s < chunk * 256 + 256; ++s)
        acc += QKV[((size_t)(b * SQ + s)) * QKVD + 2 * DM + h * DH + dh];
    __shared__ float red[256];
    red[t] = acc; __syncthreads();
    if (t < 64)
        meanV[bh * DH + dh] = (red[t] + red[64 + t] + red[128 + t] + red[192 + t]) * (1.0f / (float)SQ);
}

// ------- build context directly as bf16 hi/lo: broadcast + scatter ---------
__global__ void ctxfill2_kernel(const float* __restrict__ meanV,
                                __hip_bfloat16* __restrict__ ch,
                                __hip_bfloat16* __restrict__ cl) {
    int n = blockIdx.x * 256 + threadIdx.x;   // 0 .. 4194303
    int d = n & 511;
    int row = n >> 9;
    int b = row >> 10;
    float v = meanV[((b << 3) + (d >> 6)) * DH + (d & 63)];
    __hip_bfloat16 hb, lb; split_hl(v, hb, lb);
    ch[n] = hb; cl[n] = lb;
}

__global__ void scatter2_kernel(const float* __restrict__ upd, const int* __restrict__ Mtop,
                                __hip_bfloat16* __restrict__ ch,
                                __hip_bfloat16* __restrict__ cl) {
    int bh = blockIdx.x, u = blockIdx.y;
    int t = threadIdx.x;   // 64
    int b = bh >> 3, h = bh & 7;
    int l = Mtop[bh * NTOP + u];
    float v = upd[((size_t)bh * NTOP + u) * DH + t];
    size_t o = ((size_t)(b * SQ + l)) * DM + h * DH + t;
    __hip_bfloat16 hb, lb; split_hl(v, hb, lb);
    ch[o] = hb; cl[o] = lb;
}

// ---------------- residual add + LayerNorm (+fused split) ------------------
__global__ __launch_bounds__(256) void add_ln_kernel(const float* __restrict__ Av,
                                                     const float* __restrict__ Bv,
                                                     const float* __restrict__ g,
                                                     const float* __restrict__ be,
                                                     float* __restrict__ out,
                                                     __hip_bfloat16* __restrict__ oh,
                                                     __hip_bfloat16* __restrict__ ol) {
    int row = blockIdx.x;
    int t = threadIdx.x;
    size_t base = (size_t)row * DM;
    float v0 = Av[base + t] + Bv[base + t];
    float v1 = Av[base + 256 + t] + Bv[base + 256 + t];
    __shared__ float r1[256], r2[256];
    r1[t] = v0 + v1; r2[t] = v0 * v0 + v1 * v1;
    __syncthreads();
    for (int s = 128; s > 0; s >>= 1) {
        if (t < s) { r1[t] += r1[t + s]; r2[t] += r2[t + s]; }
        __syncthreads();
    }
    float mu = r1[0] * (1.0f / (float)DM);
    float var = r2[0] * (1.0f / (float)DM) - mu * mu;
    float rs = rsqrtf(var + EPSF);
    float o0 = (v0 - mu) * rs * g[t] + be[t];
    float o1 = (v1 - mu) * rs * g[t + 256] + be[t + 256];
    out[base + t] = o0;
    out[base + 256 + t] = o1;
    __hip_bfloat16 hb, lb;
    split_hl(o0, hb, lb); oh[base + t] = hb; ol[base + t] = lb;
    split_hl(o1, hb, lb); oh[base + 256 + t] = hb; ol[base + 256 + t] = lb;
}

// ---------------- final LN + GELU + mask -----------------------------------
__global__ __launch_bounds__(256) void final_kernel(const float* __restrict__ X,
                                                    const float* __restrict__ g,
                                                    const float* __restrict__ be,
                                                    const float* __restrict__ mark,
                                                    float* __restrict__ act) {
    int row = blockIdx.x;
    int t = threadIdx.x;
    size_t base = (size_t)row * DM;
    float v0 = X[base + t];
    float v1 = X[base + 256 + t];
    __shared__ float r1[256], r2[256];
    r1[t] = v0 + v1; r2[t] = v0 * v0 + v1 * v1;
    __syncthreads();
    for (int s = 128; s > 0; s >>= 1) {
        if (t < s) { r1[t] += r1[t + s]; r2[t] += r2[t + s]; }
        __syncthreads();
    }
    float mu = r1[0] * (1.0f / (float)DM);
    float var = r2[0] * (1.0f / (float)DM) - mu * mu;
    float rs = rsqrtf(var + EPSF);
    float mk = mark[row];
    float a0 = (v0 - mu) * rs * g[t] + be[t];
    float a1 = (v1 - mu) * rs * g[t + 256] + be[t + 256];
    act[base + t] = gelu_f(a0) * mk;
    act[base + 256 + t] = gelu_f(a1) * mk;
}

// ---------------- final projection: two-stage ------------------------------
__global__ __launch_bounds__(256) void proj1_kernel(const float* __restrict__ act,
                                                    const float* __restrict__ pw,
                                                    float* __restrict__ part) {
    int bc = blockIdx.x;      // 40
    int sg = blockIdx.y;      // 16
    int b = bc / 5, c = bc % 5;
    const float4* a = reinterpret_cast<const float4*>(act + (size_t)b * (SQ * DM) + sg * 32768);
    const float4* w = reinterpret_cast<const float4*>(pw + (size_t)c * (SQ * DM) + sg * 32768);
    float s = 0.f;
    for (int i = threadIdx.x; i < 8192; i += 256) {
        float4 av = a[i], wv = w[i];
        s += av.x * wv.x + av.y * wv.y + av.z * wv.z + av.w * wv.w;
    }
    __shared__ float red[256];
    red[threadIdx.x] = s; __syncthreads();
    for (int sft = 128; sft > 0; sft >>= 1) {
        if (threadIdx.x < sft) red[threadIdx.x] += red[threadIdx.x + sft];
        __syncthreads();
    }
    if (threadIdx.x == 0) part[bc * 16 + sg] = red[0];
}

__global__ void proj2_kernel(const float* __restrict__ part, const float* __restrict__ pb,
                             float* __restrict__ out) {
    int t = threadIdx.x;  // 64
    if (t < 40) {
        float s = 0.f;
        #pragma unroll
        for (int i = 0; i < 16; ++i) s += part[t * 16 + i];
        out[t] = s + pb[t % 5];
    }
}

// ---------------------------------------------------------------------------
extern "C" void kernel_launch(void* const* d_in, const int* in_sizes, int n_in,
                              void* d_out, int out_size, void* d_ws, size_t ws_size,
                              hipStream_t stream) {
    (void)in_sizes; (void)n_in; (void)out_size; (void)ws_size;

    const float* x_enc      = (const float*)d_in[0];
    const float* x_mark_enc = (const float*)d_in[1];
    const float* token_k    = (const float*)d_in[2];
    const float* Wq = (const float*)d_in[3];
    const float* bq = (const float*)d_in[4];
    const float* Wk = (const float*)d_in[5];
    const float* bk = (const float*)d_in[6];
    const float* Wv = (const float*)d_in[7];
    const float* bv = (const float*)d_in[8];
    const float* Wo = (const float*)d_in[9];
    const float* bo = (const float*)d_in[10];
    const float* c1w = (const float*)d_in[11];
    const float* c1b = (const float*)d_in[12];
    const float* c2w = (const float*)d_in[13];
    const float* c2b = (const float*)d_in[14];
    const float* g1 = (const float*)d_in[15];
    const float* b1 = (const float*)d_in[16];
    const float* g2 = (const float*)d_in[17];
    const float* b2 = (const float*)d_in[18];
    const float* gf = (const float*)d_in[19];
    const float* bf = (const float*)d_in[20];
    const float* proj_w = (const float*)d_in[21];
    const float* proj_b = (const float*)d_in[22];
    float* out = (float*)d_out;

    const size_t MB = 1024 * 1024;
    char* wsb = (char*)d_ws;
    // fp32 regions / time-multiplexed map:
    //  0..16   X (fp32 residual)      | during FFN: Yh first half
    //  16..64  QKV fp32               | after attn: CTXh(16..24) CTXl(24..32),
    //                                 | during FFN: Yh second half(?)/Yl
    float* X    = (float*)(wsb);                  // 0..16
    float* QKVp = (float*)(wsb + 16 * MB);        // 16..64 (8192x1536 fp32)
    __hip_bfloat16* CTXh = (__hip_bfloat16*)(wsb + 16 * MB);  // 16..24
    __hip_bfloat16* CTXl = (__hip_bfloat16*)(wsb + 24 * MB);  // 24..32
    __hip_bfloat16* Yh   = (__hip_bfloat16*)(wsb);            // 0..32 (X+CTX dead)
    __hip_bfloat16* Yl   = (__hip_bfloat16*)(wsb + 32 * MB);  // 32..64
    float* X1p  = (float*)(wsb + 64 * MB);        // 64..80
    float* NXp  = (float*)(wsb + 80 * MB);        // 80..96
    __hip_bfloat16* Xh  = (__hip_bfloat16*)(wsb + 96 * MB);   // 96..104
    __hip_bfloat16* Xl  = (__hip_bfloat16*)(wsb + 104 * MB);  // 104..112
    __hip_bfloat16* X1h = (__hip_bfloat16*)(wsb + 112 * MB);  // 112..120
    __hip_bfloat16* X1l = (__hip_bfloat16*)(wsb + 120 * MB);  // 120..128
    __hip_bfloat16* WhA = (__hip_bfloat16*)(wsb + 128 * MB);  // 128..130
    __hip_bfloat16* WlA = (__hip_bfloat16*)(wsb + 130 * MB);  // 130..132
    __hip_bfloat16* WhB = (__hip_bfloat16*)(wsb + 132 * MB);  // 132..134
    __hip_bfloat16* WlB = (__hip_bfloat16*)(wsb + 134 * MB);  // 134..136
    char* smal = wsb + 136 * MB;
    float* biasC = (float*)(smal);                            // 8 KB
    int*   IDX   = (int*)(smal + 8 * 1024);                   // 140 KB -> 160
    int*   MTOP  = (int*)(smal + 168 * 1024);                 // 9 KB -> 16
    float* MEANV = (float*)(smal + 184 * 1024);               // 16 KB
    float* PART  = (float*)(smal + 200 * 1024);               // 8 KB
    float* MX    = (float*)(smal + 256 * 1024);               // 1 MB
    float* SM    = (float*)(smal + 1280 * 1024);              // 1 MB
    float* UPD   = (float*)(smal + 2304 * 1024);              // 560 KB -> 576
    float* PM    = (float*)(smal + 2880 * 1024);              // 70 KB -> 96
    float* PL    = (float*)(smal + 2976 * 1024);              // 70 KB -> 96
    float* PACC  = (float*)(smal + 3072 * 1024);              // 4.6 MB

    embed_kernel<<<ROWS, 256, 0, stream>>>(x_enc, token_k, X, Xh, Xl);

    for (int lyr = 0; lyr < 3; ++lyr) {
        const float* Wq_l = Wq + (size_t)lyr * DM * DM;
        const float* bq_l = bq + (size_t)lyr * DM;
        const float* Wk_l = Wk + (size_t)lyr * DM * DM;
        const float* bk_l = bk + (size_t)lyr * DM;
        const float* Wv_l = Wv + (size_t)lyr * DM * DM;
        const float* bv_l = bv + (size_t)lyr * DM;
        const float* Wo_l = Wo + (size_t)lyr * DM * DM;
        const float* bo_l = bo + (size_t)lyr * DM;
        const float* c1w_l = c1w + (size_t)lyr * DFF * DM;
        const float* c1b_l = c1b + (size_t)lyr * DFF;
        const float* c2w_l = c2w + (size_t)lyr * DM * DFF;
        const float* c2b_l = c2b + (size_t)lyr * DM;
        const float* g1_l = g1 + (size_t)lyr * DM;
        const float* b1_l = b1 + (size_t)lyr * DM;
        const float* g2_l = g2 + (size_t)lyr * DM;
        const float* b2_l = b2 + (size_t)lyr * DM;

        // ---- fused QKV projection (N=1536) ----
        split_kernel<<<(DM * DM / 4 + 255) / 256, 256, 0, stream>>>(Wq_l, WhA, WlA, DM * DM / 4);
        split_kernel<<<(DM * DM / 4 + 255) / 256, 256, 0, stream>>>(Wk_l, WhA + DM * DM, WlA + DM * DM, DM * DM / 4);
        split_kernel<<<(DM * DM / 4 + 255) / 256, 256, 0, stream>>>(Wv_l, WhA + 2 * DM * DM, WlA + 2 * DM * DM, DM * DM / 4);
        catbias_kernel<<<1, 512, 0, stream>>>(bq_l, bk_l, bv_l, biasC);
        mfma_gemm<128, 0><<<dim3(ROWS / 128, QKVD / 128), 256, 0, stream>>>(
            Xh, Xl, WhA, WlA, biasC, QKVp, nullptr, nullptr, ROWS, QKVD, DM);

        // ---- ProbSparse attention ----
        idx_kernel<<<(SQ * NTOP + 255) / 256, 256, 0, stream>>>(lyr, IDX);
        mscore_part<<<dim3(64, 8, SSPLIT), 128, 0, stream>>>(QKVp, IDX, MX, SM);
        topk_kernel<<<64, 256, 0, stream>>>(MX, SM, MTOP);
        attn_part<<<dim3(64, KSPLIT), 512, 0, stream>>>(QKVp, MTOP, PACC, PM, PL);
        attn_comb<<<64, 512, 0, stream>>>(PACC, PM, PL, UPD);
        meanv_kernel<<<64, 256, 0, stream>>>(QKVp, MEANV);
        // QKV fp32 dead now; write context straight into its region as h/l
        ctxfill2_kernel<<<(ROWS * DM) / 256, 256, 0, stream>>>(MEANV, CTXh, CTXl);
        scatter2_kernel<<<dim3(64, NTOP), 64, 0, stream>>>(UPD, MTOP, CTXh, CTXl);

        // ---- attention out-projection ----
        split_kernel<<<(DM * DM / 4 + 255) / 256, 256, 0, stream>>>(Wo_l, WhB, WlB, DM * DM / 4);
        mfma_gemm<64, 0><<<dim3(ROWS / 128, DM / 64), 256, 0, stream>>>(
            CTXh, CTXl, WhB, WlB, bo_l, NXp, nullptr, nullptr, ROWS, DM, DM);
        add_ln_kernel<<<ROWS, 256, 0, stream>>>(X, NXp, g1_l, b1_l, X1p, X1h, X1l);

        // ---- FFN (unchunked; Y occupies 0..64MB where X/CTX/QKV are dead) ----
        split_kernel<<<(DFF * DM / 4 + 255) / 256, 256, 0, stream>>>(c1w_l, WhA, WlA, DFF * DM / 4);
        split_kernel<<<(DM * DFF / 4 + 255) / 256, 256, 0, stream>>>(c2w_l, WhB, WlB, DM * DFF / 4);
        mfma_gemm<128, 2><<<dim3(ROWS / 128, DFF / 128), 256, 0, stream>>>(
            X1h, X1l, WhA, WlA, c1b_l, nullptr, Yh, Yl, ROWS, DFF, DM);
        mfma_gemm<64, 0><<<dim3(ROWS / 128, DM / 64), 256, 0, stream>>>(
            Yh, Yl, WhB, WlB, c2b_l, NXp, nullptr, nullptr, ROWS, DM, DFF);
        add_ln_kernel<<<ROWS, 256, 0, stream>>>(X1p, NXp, g2_l, b2_l, X, Xh, Xl);
    }

    final_kernel<<<ROWS, 256, 0, stream>>>(X, gf, bf, x_mark_enc, (float*)QKVp);
    proj1_kernel<<<dim3(40, 16), 256, 0, stream>>>((float*)QKVp, proj_w, PART);
    proj2_kernel<<<1, 64, 0, stream>>>(PART, proj_b, out);
}